// Round 1
// baseline (1394.773 us; speedup 1.0000x reference)
//
#include <hip/hip_runtime.h>
#include <hip/hip_bf16.h>
#include <math.h>

// Problem constants (from reference): B=4, S=1024, E=1024, H=16, D=64
#define B_ 4
#define S_ 1024
#define E_ 1024
#define H_ 16
#define D_ 64

// ---------------------------------------------------------------------------
// Kernel 1: QKV projection.  Y[b,h,s,d] = sum_e x[b,s,e] * W[h,e,d]
// One block computes a 64(S) x 64(D) tile for one (b,h,weight).
// block = 256 threads, each thread computes a 4x4 register tile.
// ---------------------------------------------------------------------------
__global__ __launch_bounds__(256) void qkv_kernel(
    const float* __restrict__ x,
    const float* __restrict__ Wq,
    const float* __restrict__ Wk,
    const float* __restrict__ Wv,
    float* __restrict__ q, float* __restrict__ k, float* __restrict__ v)
{
    const int stile = blockIdx.x;            // 0..S/64-1
    const int bh    = blockIdx.y;            // 0..B*H-1
    const int b     = bh >> 4;
    const int h     = bh & 15;
    const int w     = blockIdx.z;            // 0=q,1=k,2=v

    const float* W = (w == 0) ? Wq : (w == 1) ? Wk : Wv;
    float*       Y = (w == 0) ? q  : (w == 1) ? k  : v;

    __shared__ float Xs[64][17];   // 64 rows x 16 k, +1 pad
    __shared__ float Ws[16][65];   // 16 k x 64 cols, +1 pad

    const int tid = threadIdx.x;
    const int tx  = tid & 15;
    const int ty  = tid >> 4;

    float acc[4][4] = {};

    const float* xb = x + ((size_t)b * S_ + (size_t)stile * 64) * E_;
    const float* Wh = W + (size_t)h * E_ * D_;

    for (int e0 = 0; e0 < E_; e0 += 16) {
        // load X tile: 64x16 = 1024 elems, 4 per thread
        #pragma unroll
        for (int i = 0; i < 4; i++) {
            int idx = tid + i * 256;
            int r = idx >> 4, c = idx & 15;
            Xs[r][c] = xb[(size_t)r * E_ + e0 + c];
        }
        // load W tile: 16x64 = 1024 elems
        #pragma unroll
        for (int i = 0; i < 4; i++) {
            int idx = tid + i * 256;
            int r = idx >> 6, c = idx & 63;
            Ws[r][c] = Wh[(size_t)(e0 + r) * D_ + c];
        }
        __syncthreads();
        #pragma unroll
        for (int kk = 0; kk < 16; kk++) {
            float a0[4], b0[4];
            #pragma unroll
            for (int i = 0; i < 4; i++) a0[i] = Xs[ty * 4 + i][kk];
            #pragma unroll
            for (int j = 0; j < 4; j++) b0[j] = Ws[kk][tx * 4 + j];
            #pragma unroll
            for (int i = 0; i < 4; i++)
                #pragma unroll
                for (int j = 0; j < 4; j++)
                    acc[i][j] += a0[i] * b0[j];
        }
        __syncthreads();
    }

    float* Yb = Y + ((size_t)bh * S_ + (size_t)stile * 64) * D_;
    #pragma unroll
    for (int i = 0; i < 4; i++)
        #pragma unroll
        for (int j = 0; j < 4; j++)
            Yb[(size_t)(ty * 4 + i) * D_ + tx * 4 + j] = acc[i][j];
}

// ---------------------------------------------------------------------------
// Kernel 2: causal flash attention per (b,h).  64-row Q tile per block.
// Online softmax; K/V tiles of 64 rows staged in LDS.
// concat[b,s,h*D+d] = softmax(QK^T/sqrt(D)) @ V
// ---------------------------------------------------------------------------
__global__ __launch_bounds__(256) void attn_kernel(
    const float* __restrict__ q,
    const float* __restrict__ k,
    const float* __restrict__ v,
    float* __restrict__ concat)
{
    const int qt = blockIdx.x;     // q tile (64 rows)
    const int bh = blockIdx.y;
    const int b  = bh >> 4;
    const int h  = bh & 15;

    const float* Q = q + ((size_t)bh * S_ + (size_t)qt * 64) * D_;
    const float* K = k + (size_t)bh * S_ * D_;
    const float* V = v + (size_t)bh * S_ * D_;

    __shared__ float Qs[64][D_ + 1];
    __shared__ float Ks[64][D_ + 1];
    __shared__ float Vs[64][D_ + 1];
    __shared__ float Ss[64][65];
    __shared__ float red[64][8];   // [0..3] partial max, [4..7] partial sum

    const int tid = threadIdx.x;
    // score-compute mapping (4x4 per thread)
    const int tx = tid & 15;
    const int ty = tid >> 4;
    // softmax / PV mapping: row r, quarter qq
    const int r  = tid >> 2;       // 0..63
    const int qq = tid & 3;        // 0..3

    // load Q tile (4096 elems, 16/thread)
    #pragma unroll
    for (int i = 0; i < 16; i++) {
        int idx = tid + i * 256;
        int rr = idx >> 6, cc = idx & 63;
        Qs[rr][cc] = Q[(size_t)rr * D_ + cc];
    }

    float m = -INFINITY;
    float l = 0.0f;
    float acc[16];
    #pragma unroll
    for (int c = 0; c < 16; c++) acc[c] = 0.0f;

    const float scale = 0.125f;    // 1/sqrt(64)

    for (int kt = 0; kt <= qt; kt++) {
        __syncthreads();           // prev iter's reads of Ks/Vs/Ss done
        // load K,V tiles
        #pragma unroll
        for (int i = 0; i < 16; i++) {
            int idx = tid + i * 256;
            int rr = idx >> 6, cc = idx & 63;
            Ks[rr][cc] = K[((size_t)kt * 64 + rr) * D_ + cc];
            Vs[rr][cc] = V[((size_t)kt * 64 + rr) * D_ + cc];
        }
        __syncthreads();

        // scores: 4x4 per thread
        float sc[4][4] = {};
        #pragma unroll
        for (int d = 0; d < D_; d++) {
            float a0[4], b0[4];
            #pragma unroll
            for (int i = 0; i < 4; i++) a0[i] = Qs[ty * 4 + i][d];
            #pragma unroll
            for (int j = 0; j < 4; j++) b0[j] = Ks[tx * 4 + j][d];
            #pragma unroll
            for (int i = 0; i < 4; i++)
                #pragma unroll
                for (int j = 0; j < 4; j++)
                    sc[i][j] += a0[i] * b0[j];
        }
        #pragma unroll
        for (int i = 0; i < 4; i++) {
            #pragma unroll
            for (int j = 0; j < 4; j++) {
                float sv = sc[i][j] * scale;
                if (kt == qt && (tx * 4 + j) > (ty * 4 + i)) sv = -INFINITY;
                Ss[ty * 4 + i][tx * 4 + j] = sv;
            }
        }
        __syncthreads();

        // online softmax, row-mapped: thread owns row r, cols qq*16..qq*16+15
        float pm = -INFINITY;
        #pragma unroll
        for (int c = 0; c < 16; c++) pm = fmaxf(pm, Ss[r][qq * 16 + c]);
        red[r][qq] = pm;
        __syncthreads();

        float mnew = fmaxf(fmaxf(red[r][0], red[r][1]), fmaxf(red[r][2], red[r][3]));
        mnew = fmaxf(m, mnew);
        float rscale = __expf(m - mnew);
        m = mnew;

        float psum = 0.0f;
        #pragma unroll
        for (int c = 0; c < 16; c++) {
            float p = __expf(Ss[r][qq * 16 + c] - mnew);
            Ss[r][qq * 16 + c] = p;
            psum += p;
        }
        red[r][4 + qq] = psum;
        __syncthreads();

        l = l * rscale + (red[r][4] + red[r][5] + red[r][6] + red[r][7]);

        // PV: thread owns row r, d-cols qq*16..+16
        #pragma unroll
        for (int c = 0; c < 16; c++) acc[c] *= rscale;
        for (int kk = 0; kk < 64; kk++) {
            float pf = Ss[r][kk];
            #pragma unroll
            for (int c = 0; c < 16; c++)
                acc[c] += pf * Vs[kk][qq * 16 + c];
        }
    }

    // write: concat[b][qt*64+r][h*64 + qq*16 + c]
    float inv_l = 1.0f / l;
    size_t base = ((size_t)b * S_ + (size_t)qt * 64 + r) * E_ + (size_t)h * D_ + qq * 16;
    #pragma unroll
    for (int c = 0; c < 16; c++)
        concat[base + c] = acc[c] * inv_l;
}

// ---------------------------------------------------------------------------
// Kernel 3: output GEMM.  out[b,i,j] = sum_s W_O[i,s] * concat[b,s,j]
// (reference does jnp.matmul(W_O, concat): contraction over the S axis)
// ---------------------------------------------------------------------------
__global__ __launch_bounds__(256) void out_kernel(
    const float* __restrict__ W_O,
    const float* __restrict__ concat,
    float* __restrict__ out)
{
    const int jt = blockIdx.x;     // col tile
    const int it = blockIdx.y;     // row tile
    const int b  = blockIdx.z;

    __shared__ float As[64][17];
    __shared__ float Bs[16][65];

    const int tid = threadIdx.x;
    const int tx  = tid & 15;
    const int ty  = tid >> 4;

    float acc[4][4] = {};

    const float* cb = concat + (size_t)b * S_ * E_;

    for (int s0 = 0; s0 < S_; s0 += 16) {
        #pragma unroll
        for (int i = 0; i < 4; i++) {
            int idx = tid + i * 256;
            int rr = idx >> 4, cc = idx & 15;
            As[rr][cc] = W_O[(size_t)(it * 64 + rr) * S_ + s0 + cc];
        }
        #pragma unroll
        for (int i = 0; i < 4; i++) {
            int idx = tid + i * 256;
            int rr = idx >> 6, cc = idx & 63;
            Bs[rr][cc] = cb[(size_t)(s0 + rr) * E_ + jt * 64 + cc];
        }
        __syncthreads();
        #pragma unroll
        for (int kk = 0; kk < 16; kk++) {
            float a0[4], b0[4];
            #pragma unroll
            for (int i = 0; i < 4; i++) a0[i] = As[ty * 4 + i][kk];
            #pragma unroll
            for (int j = 0; j < 4; j++) b0[j] = Bs[kk][tx * 4 + j];
            #pragma unroll
            for (int i = 0; i < 4; i++)
                #pragma unroll
                for (int j = 0; j < 4; j++)
                    acc[i][j] += a0[i] * b0[j];
        }
        __syncthreads();
    }

    #pragma unroll
    for (int i = 0; i < 4; i++)
        #pragma unroll
        for (int j = 0; j < 4; j++)
            out[((size_t)b * E_ + it * 64 + ty * 4 + i) * E_ + jt * 64 + tx * 4 + j] = acc[i][j];
}

// ---------------------------------------------------------------------------
extern "C" void kernel_launch(void* const* d_in, const int* in_sizes, int n_in,
                              void* d_out, int out_size, void* d_ws, size_t ws_size,
                              hipStream_t stream)
{
    const float* x   = (const float*)d_in[0];
    const float* Wq  = (const float*)d_in[1];
    const float* Wk  = (const float*)d_in[2];
    const float* Wv  = (const float*)d_in[3];
    const float* W_O = (const float*)d_in[4];
    float* out = (float*)d_out;

    float* ws = (float*)d_ws;
    const size_t qkv_elems = (size_t)B_ * H_ * S_ * D_;   // 4.19M floats each
    float* q      = ws;
    float* k      = q + qkv_elems;
    float* v      = k + qkv_elems;
    float* concat = v + qkv_elems;                        // B*S*E floats

    qkv_kernel<<<dim3(S_ / 64, B_ * H_, 3), 256, 0, stream>>>(x, Wq, Wk, Wv, q, k, v);
    attn_kernel<<<dim3(S_ / 64, B_ * H_), 256, 0, stream>>>(q, k, v, concat);
    out_kernel<<<dim3(E_ / 64, E_ / 64, B_), 256, 0, stream>>>(W_O, concat, out);
}

// Round 3
// 373.512 us; speedup vs baseline: 3.7342x; 3.7342x over previous
//
#include <hip/hip_runtime.h>
#include <hip/hip_bf16.h>
#include <math.h>

#define B_ 4
#define S_ 1024
#define E_ 1024
#define H_ 16
#define D_ 64

typedef __attribute__((ext_vector_type(8))) short   s16x8;
typedef __attribute__((ext_vector_type(8))) unsigned short u16x8;
typedef __attribute__((ext_vector_type(4))) unsigned short u16x4;
typedef __attribute__((ext_vector_type(4))) float   f32x4;
typedef unsigned short u16;

// round-to-nearest-even fp32 -> bf16 bits
__device__ __forceinline__ u16 f2bf(float f) {
    union { float f; unsigned u; } v; v.f = f;
    unsigned u = v.u + 0x7FFFu + ((v.u >> 16) & 1u);
    return (u16)(u >> 16);
}
__device__ __forceinline__ float bf2f(u16 h) {
    union { unsigned u; float f; } v; v.u = ((unsigned)h) << 16;
    return v.f;
}
__device__ __forceinline__ void splitf(float f, u16& h, u16& l) {
    h = f2bf(f);
    l = f2bf(f - bf2f(h));
}

#define MFMA(a, b, c) __builtin_amdgcn_mfma_f32_16x16x32_bf16((a), (b), (c), 0, 0, 0)

#define LDR 40   // LDS row stride in bf16 elems (32 data + 8 pad = 80 B, 16B-aligned)

// ---------------------------------------------------------------------------
// Kernel 1: QKV projection as one GEMM.
//   Y[(b,s)][n] = sum_e X[(b,s)][e] * Wall[e][n],  n = w*1024 + h*64 + d
// 128x128 tile / block, 4 waves (2x2 of 64x64), BK=32, bf16 hi/lo x3 MFMA.
// Q,K stored [b,h,s,d]; V stored transposed [b,h,d,s] (natural frag store).
// ---------------------------------------------------------------------------
__global__ __launch_bounds__(256) void qkv_gemm(
    const float* __restrict__ x,
    const float* __restrict__ Wq, const float* __restrict__ Wk, const float* __restrict__ Wv,
    float* __restrict__ q, float* __restrict__ k, float* __restrict__ vT)
{
    __shared__ __align__(16) u16 Ah[128][LDR], Al[128][LDR], Bh[128][LDR], Bl[128][LDR];

    const int tid  = threadIdx.x;
    const int m0   = blockIdx.x * 128;          // (b,s) rows
    const int n0   = blockIdx.y * 128;          // (w,h,d) cols
    const int w    = n0 >> 10;
    const int h0   = (n0 & 1023) >> 6;
    const float* W = (w == 0) ? Wq : (w == 1) ? Wk : Wv;

    const int wid  = tid >> 6, lane = tid & 63;
    const int wr   = wid >> 1, wc = wid & 1;
    const int lrow = lane & 15, lk = lane >> 4;

    // staging maps
    const int sr = tid >> 1;            // A row 0..127
    const int sh = (tid & 1) * 16;      // A k-half
    const int bn = tid & 127;           // B n 0..127
    const int bk = (tid >> 7) * 16;     // B k-half

    f32x4 acc[4][4] = {};

    for (int k0 = 0; k0 < E_; k0 += 32) {
        __syncthreads();
        // ---- stage A: X rows, fp32 -> hi/lo split (16 elems/thread)
        {
            const float* xp = x + (size_t)(m0 + sr) * E_ + k0 + sh;
            f32x4 a0 = *(const f32x4*)(xp);
            f32x4 a1 = *(const f32x4*)(xp + 4);
            f32x4 a2 = *(const f32x4*)(xp + 8);
            f32x4 a3 = *(const f32x4*)(xp + 12);
            u16x8 h0v, l0v, h1v, l1v;
            #pragma unroll
            for (int j = 0; j < 4; j++) {
                u16 hh, ll;
                splitf(a0[j], hh, ll); h0v[j]     = hh; l0v[j]     = ll;
                splitf(a1[j], hh, ll); h0v[j + 4] = hh; l0v[j + 4] = ll;
                splitf(a2[j], hh, ll); h1v[j]     = hh; l1v[j]     = ll;
                splitf(a3[j], hh, ll); h1v[j + 4] = hh; l1v[j + 4] = ll;
            }
            *(u16x8*)&Ah[sr][sh]     = h0v;  *(u16x8*)&Al[sr][sh]     = l0v;
            *(u16x8*)&Ah[sr][sh + 8] = h1v;  *(u16x8*)&Al[sr][sh + 8] = l1v;
        }
        // ---- stage B: W gather (transpose to n-major), coalesced across lanes
        {
            const int nh = h0 + (bn >> 6);
            const int nd = bn & 63;
            const float* wp = W + ((size_t)nh * E_ + k0 + bk) * D_ + nd;
            float fb[16];
            #pragma unroll
            for (int i = 0; i < 16; i++) fb[i] = wp[(size_t)i * D_];
            u16x8 h0v, l0v, h1v, l1v;
            #pragma unroll
            for (int j = 0; j < 8; j++) {
                u16 hh, ll;
                splitf(fb[j], hh, ll);     h0v[j] = hh; l0v[j] = ll;
                splitf(fb[j + 8], hh, ll); h1v[j] = hh; l1v[j] = ll;
            }
            *(u16x8*)&Bh[bn][bk]     = h0v;  *(u16x8*)&Bl[bn][bk]     = l0v;
            *(u16x8*)&Bh[bn][bk + 8] = h1v;  *(u16x8*)&Bl[bn][bk + 8] = l1v;
        }
        __syncthreads();

        s16x8 fAh[4], fAl[4], fBh[4], fBl[4];
        #pragma unroll
        for (int i = 0; i < 4; i++) {
            fAh[i] = *(const s16x8*)&Ah[wr * 64 + i * 16 + lrow][lk * 8];
            fAl[i] = *(const s16x8*)&Al[wr * 64 + i * 16 + lrow][lk * 8];
            fBh[i] = *(const s16x8*)&Bh[wc * 64 + i * 16 + lrow][lk * 8];
            fBl[i] = *(const s16x8*)&Bl[wc * 64 + i * 16 + lrow][lk * 8];
        }
        #pragma unroll
        for (int i = 0; i < 4; i++)
            #pragma unroll
            for (int j = 0; j < 4; j++) {
                acc[i][j] = MFMA(fAh[i], fBh[j], acc[i][j]);
                acc[i][j] = MFMA(fAl[i], fBh[j], acc[i][j]);
                acc[i][j] = MFMA(fAh[i], fBl[j], acc[i][j]);
            }
    }

    // ---- epilogue
    if (w < 2) {
        float* Y = (w == 0) ? q : k;
        #pragma unroll
        for (int i = 0; i < 4; i++) {
            const int mrow = m0 + wr * 64 + i * 16 + lk * 4;
            const int b = mrow >> 10, s = mrow & 1023;
            #pragma unroll
            for (int j = 0; j < 4; j++) {
                const int n = n0 + wc * 64 + j * 16 + lrow;
                const int hh = (n & 1023) >> 6, d = n & 63;
                float* dst = Y + (((size_t)b * H_ + hh) * S_ + s) * D_ + d;
                #pragma unroll
                for (int r = 0; r < 4; r++) dst[(size_t)r * D_] = acc[i][j][r];
            }
        }
    } else {
        #pragma unroll
        for (int i = 0; i < 4; i++) {
            const int mrow = m0 + wr * 64 + i * 16 + lk * 4;
            const int b = mrow >> 10, s = mrow & 1023;
            #pragma unroll
            for (int j = 0; j < 4; j++) {
                const int n = n0 + wc * 64 + j * 16 + lrow;
                const int hh = (n & 1023) >> 6, d = n & 63;
                float* dst = vT + (((size_t)b * H_ + hh) * D_ + d) * S_ + s;
                *(f32x4*)dst = acc[i][j];   // s-contiguous
            }
        }
    }
}

// ---------------------------------------------------------------------------
// Kernel 2: causal flash attention, MFMA bf16x3.
// Block = (qt, bh): 4 waves x 16 q-rows, KVBLK=32 staged hi/lo in LDS.
// Output: concatT hi/lo bf16, layout [b][e][s].
// ---------------------------------------------------------------------------
__global__ __launch_bounds__(256) void attn(
    const float* __restrict__ q, const float* __restrict__ k, const float* __restrict__ vT,
    u16* __restrict__ CTh, u16* __restrict__ CTl)
{
    const int qt = blockIdx.x;
    const int bh = blockIdx.y;

    __shared__ __align__(16) u16 Kh[32][72], Kl[32][72];
    __shared__ __align__(16) u16 Vh[64][LDR], Vl[64][LDR];
    __shared__ __align__(16) u16 Ph[4][16][LDR], Pl[4][16][LDR];

    const int tid = threadIdx.x, wid = tid >> 6, lane = tid & 63;
    const int lrow = lane & 15, lk = lane >> 4;
    const int q0g = qt * 64 + wid * 16;       // wave's first global q row

    // Q fragments direct from global (scaled by 1/sqrt(D)=0.125, exact), hi/lo
    s16x8 fQh[2], fQl[2];
    {
        const float* Qp = q + ((size_t)bh * S_ + q0g + lrow) * D_;
        #pragma unroll
        for (int ks = 0; ks < 2; ks++) {
            f32x4 q0 = *(const f32x4*)(Qp + ks * 32 + lk * 8);
            f32x4 q1 = *(const f32x4*)(Qp + ks * 32 + lk * 8 + 4);
            u16x8 hv, lv;
            #pragma unroll
            for (int j = 0; j < 4; j++) {
                u16 hh, ll;
                splitf(q0[j] * 0.125f, hh, ll); hv[j]     = hh; lv[j]     = ll;
                splitf(q1[j] * 0.125f, hh, ll); hv[j + 4] = hh; lv[j + 4] = ll;
            }
            fQh[ks] = (s16x8)hv; fQl[ks] = (s16x8)lv;
        }
    }

    f32x4 accO[4] = {};
    float m_r[4], l_r[4];
    #pragma unroll
    for (int r = 0; r < 4; r++) { m_r[r] = -INFINITY; l_r[r] = 0.0f; }

    const float* Kbase = k  + (size_t)bh * S_ * D_;
    const float* Vbase = vT + (size_t)bh * D_ * S_;
    const int ntiles = 2 * qt + 2;

    for (int t = 0; t < ntiles; t++) {
        const int c0 = t * 32;
        __syncthreads();    // prev PV reads / P reads done before overwrite
        // ---- stage K [32 sk][64 d] and V [64 d][32 sk], fp32 -> hi/lo
        {
            const int r_ = tid >> 3, c_ = (tid & 7) * 8;
            const float* kp = Kbase + (size_t)(c0 + r_) * D_ + c_;
            f32x4 k0v = *(const f32x4*)(kp);
            f32x4 k1v = *(const f32x4*)(kp + 4);
            u16x8 hv, lv;
            #pragma unroll
            for (int j = 0; j < 4; j++) {
                u16 hh, ll;
                splitf(k0v[j], hh, ll); hv[j]     = hh; lv[j]     = ll;
                splitf(k1v[j], hh, ll); hv[j + 4] = hh; lv[j + 4] = ll;
            }
            *(u16x8*)&Kh[r_][c_] = hv;  *(u16x8*)&Kl[r_][c_] = lv;

            const int rv = tid >> 2, cv = (tid & 3) * 8;
            const float* vp = Vbase + (size_t)rv * S_ + c0 + cv;
            f32x4 v0v = *(const f32x4*)(vp);
            f32x4 v1v = *(const f32x4*)(vp + 4);
            #pragma unroll
            for (int j = 0; j < 4; j++) {
                u16 hh, ll;
                splitf(v0v[j], hh, ll); hv[j]     = hh; lv[j]     = ll;
                splitf(v1v[j], hh, ll); hv[j + 4] = hh; lv[j + 4] = ll;
            }
            *(u16x8*)&Vh[rv][cv] = hv;  *(u16x8*)&Vl[rv][cv] = lv;
        }
        __syncthreads();

        const bool active = (c0 <= q0g + 15);
        if (active) {
            // ---- scores: S[16 sq][32 sk]
            s16x8 fKh[2][2], fKl[2][2];
            #pragma unroll
            for (int nf = 0; nf < 2; nf++)
                #pragma unroll
                for (int ks = 0; ks < 2; ks++) {
                    fKh[nf][ks] = *(const s16x8*)&Kh[nf * 16 + lrow][ks * 32 + lk * 8];
                    fKl[nf][ks] = *(const s16x8*)&Kl[nf * 16 + lrow][ks * 32 + lk * 8];
                }
            f32x4 accS[2] = {};
            #pragma unroll
            for (int nf = 0; nf < 2; nf++)
                #pragma unroll
                for (int ks = 0; ks < 2; ks++) {
                    accS[nf] = MFMA(fQh[ks], fKh[nf][ks], accS[nf]);
                    accS[nf] = MFMA(fQl[ks], fKh[nf][ks], accS[nf]);
                    accS[nf] = MFMA(fQh[ks], fKl[nf][ks], accS[nf]);
                }
            // ---- causal mask (partial tile only)
            if (c0 + 31 > q0g) {
                #pragma unroll
                for (int nf = 0; nf < 2; nf++)
                    #pragma unroll
                    for (int r = 0; r < 4; r++) {
                        const int sk = c0 + nf * 16 + lrow;
                        const int sq = q0g + lk * 4 + r;
                        if (sk > sq) accS[nf][r] = -INFINITY;
                    }
            }
            // ---- online softmax (rows spread over 16 lanes)
            float p0[4], p1[4], rs[4];
            #pragma unroll
            for (int r = 0; r < 4; r++) {
                float v = fmaxf(accS[0][r], accS[1][r]);
                #pragma unroll
                for (int d_ = 1; d_ < 16; d_ <<= 1) v = fmaxf(v, __shfl_xor(v, d_));
                const float mnew = fmaxf(m_r[r], v);
                rs[r] = __expf(m_r[r] - mnew);
                m_r[r] = mnew;
                p0[r] = __expf(accS[0][r] - mnew);
                p1[r] = __expf(accS[1][r] - mnew);
                float sum = p0[r] + p1[r];
                #pragma unroll
                for (int d_ = 1; d_ < 16; d_ <<= 1) sum += __shfl_xor(sum, d_);
                l_r[r] = l_r[r] * rs[r] + sum;
            }
            // ---- write P hi/lo (transpose through LDS)
            #pragma unroll
            for (int r = 0; r < 4; r++) {
                u16 hh, ll;
                splitf(p0[r], hh, ll);
                Ph[wid][lk * 4 + r][lrow]      = hh;  Pl[wid][lk * 4 + r][lrow]      = ll;
                splitf(p1[r], hh, ll);
                Ph[wid][lk * 4 + r][16 + lrow] = hh;  Pl[wid][lk * 4 + r][16 + lrow] = ll;
            }
            // ---- rescale O
            #pragma unroll
            for (int df = 0; df < 4; df++)
                #pragma unroll
                for (int r = 0; r < 4; r++) accO[df][r] *= rs[r];
        }
        __syncthreads();
        if (active) {
            const s16x8 fPh = *(const s16x8*)&Ph[wid][lrow][lk * 8];
            const s16x8 fPl = *(const s16x8*)&Pl[wid][lrow][lk * 8];
            #pragma unroll
            for (int df = 0; df < 4; df++) {
                const s16x8 fVh = *(const s16x8*)&Vh[df * 16 + lrow][lk * 8];
                const s16x8 fVl = *(const s16x8*)&Vl[df * 16 + lrow][lk * 8];
                accO[df] = MFMA(fPh, fVh, accO[df]);
                accO[df] = MFMA(fPl, fVh, accO[df]);
                accO[df] = MFMA(fPh, fVl, accO[df]);
            }
        }
    }

    // ---- epilogue: normalize, write concatT hi/lo (s-contiguous)
    const int b = bh >> 4, h = bh & 15;
    float inv[4];
    #pragma unroll
    for (int r = 0; r < 4; r++) inv[r] = 1.0f / l_r[r];
    #pragma unroll
    for (int df = 0; df < 4; df++) {
        const int e = h * 64 + df * 16 + lrow;
        const int s = q0g + lk * 4;
        u16x4 oh, ol;
        #pragma unroll
        for (int r = 0; r < 4; r++) {
            u16 hh, ll;
            splitf(accO[df][r] * inv[r], hh, ll);
            oh[r] = hh; ol[r] = ll;
        }
        const size_t off = ((size_t)b * E_ + e) * S_ + s;
        *(u16x4*)(CTh + off) = oh;
        *(u16x4*)(CTl + off) = ol;
    }
}

// ---------------------------------------------------------------------------
// Kernel 3: output GEMM.  out[b][i][j] = sum_s WO[i][s] * C[b][s][j]
// Computed as D[m=j][n=i] = sum_s CT[j][s] * WO[i][s]  (both operands row-major,
// stores contiguous float4). A = CT (bf16 hi/lo direct), B = WO (fp32 split).
// ---------------------------------------------------------------------------
__global__ __launch_bounds__(256) void out_gemm(
    const u16* __restrict__ CTh, const u16* __restrict__ CTl,
    const float* __restrict__ WO, float* __restrict__ out)
{
    __shared__ __align__(16) u16 Ah[128][LDR], Al[128][LDR], Bh[128][LDR], Bl[128][LDR];

    const int tid = threadIdx.x;
    const int j0 = blockIdx.x * 128;
    const int i0 = blockIdx.y * 128;
    const int b  = blockIdx.z;

    const int wid = tid >> 6, lane = tid & 63;
    const int wr = wid >> 1, wc = wid & 1;
    const int lrow = lane & 15, lk = lane >> 4;

    const int sr = tid >> 1;
    const int sh = (tid & 1) * 16;

    f32x4 acc[4][4] = {};

    for (int k0 = 0; k0 < S_; k0 += 32) {
        __syncthreads();
        // ---- stage A: CT rows (already bf16 hi/lo) — 16 elems/thread
        {
            const size_t off = ((size_t)b * E_ + j0 + sr) * S_ + k0 + sh;
            *(u16x8*)&Ah[sr][sh]     = *(const u16x8*)(CTh + off);
            *(u16x8*)&Ah[sr][sh + 8] = *(const u16x8*)(CTh + off + 8);
            *(u16x8*)&Al[sr][sh]     = *(const u16x8*)(CTl + off);
            *(u16x8*)&Al[sr][sh + 8] = *(const u16x8*)(CTl + off + 8);
        }
        // ---- stage B: WO rows fp32 -> split
        {
            const float* wp = WO + (size_t)(i0 + sr) * S_ + k0 + sh;
            f32x4 a0 = *(const f32x4*)(wp);
            f32x4 a1 = *(const f32x4*)(wp + 4);
            f32x4 a2 = *(const f32x4*)(wp + 8);
            f32x4 a3 = *(const f32x4*)(wp + 12);
            u16x8 h0v, l0v, h1v, l1v;
            #pragma unroll
            for (int j = 0; j < 4; j++) {
                u16 hh, ll;
                splitf(a0[j], hh, ll); h0v[j]     = hh; l0v[j]     = ll;
                splitf(a1[j], hh, ll); h0v[j + 4] = hh; l0v[j + 4] = ll;
                splitf(a2[j], hh, ll); h1v[j]     = hh; l1v[j]     = ll;
                splitf(a3[j], hh, ll); h1v[j + 4] = hh; l1v[j + 4] = ll;
            }
            *(u16x8*)&Bh[sr][sh]     = h0v;  *(u16x8*)&Bl[sr][sh]     = l0v;
            *(u16x8*)&Bh[sr][sh + 8] = h1v;  *(u16x8*)&Bl[sr][sh + 8] = l1v;
        }
        __syncthreads();

        s16x8 fAh[4], fAl[4], fBh[4], fBl[4];
        #pragma unroll
        for (int i = 0; i < 4; i++) {
            fAh[i] = *(const s16x8*)&Ah[wr * 64 + i * 16 + lrow][lk * 8];
            fAl[i] = *(const s16x8*)&Al[wr * 64 + i * 16 + lrow][lk * 8];
            fBh[i] = *(const s16x8*)&Bh[wc * 64 + i * 16 + lrow][lk * 8];
            fBl[i] = *(const s16x8*)&Bl[wc * 64 + i * 16 + lrow][lk * 8];
        }
        #pragma unroll
        for (int i = 0; i < 4; i++)
            #pragma unroll
            for (int j = 0; j < 4; j++) {
                acc[i][j] = MFMA(fAh[i], fBh[j], acc[i][j]);
                acc[i][j] = MFMA(fAl[i], fBh[j], acc[i][j]);
                acc[i][j] = MFMA(fAh[i], fBl[j], acc[i][j]);
            }
    }

    // ---- store: lane col i fixed, rows j contiguous -> float4
    #pragma unroll
    for (int i = 0; i < 4; i++) {
        const int jj = j0 + wr * 64 + i * 16 + lk * 4;
        #pragma unroll
        for (int j = 0; j < 4; j++) {
            const int ii = i0 + wc * 64 + j * 16 + lrow;
            float* dst = out + ((size_t)b * E_ + ii) * E_ + jj;
            *(f32x4*)dst = acc[i][j];
        }
    }
}

// ---------------------------------------------------------------------------
extern "C" void kernel_launch(void* const* d_in, const int* in_sizes, int n_in,
                              void* d_out, int out_size, void* d_ws, size_t ws_size,
                              hipStream_t stream)
{
    const float* x   = (const float*)d_in[0];
    const float* Wq  = (const float*)d_in[1];
    const float* Wk  = (const float*)d_in[2];
    const float* Wv  = (const float*)d_in[3];
    const float* W_O = (const float*)d_in[4];
    float* out = (float*)d_out;

    const size_t NQKV = (size_t)B_ * H_ * S_ * D_;   // 4,194,304
    float* ws  = (float*)d_ws;
    float* q   = ws;
    float* k   = q + NQKV;
    float* vT  = k + NQKV;
    u16*   CTh = (u16*)(vT + NQKV);
    u16*   CTl = CTh + (size_t)B_ * S_ * E_;

    qkv_gemm<<<dim3(32, 24), 256, 0, stream>>>(x, Wq, Wk, Wv, q, k, vT);
    attn<<<dim3(16, 64), 256, 0, stream>>>(q, k, vT, CTh, CTl);
    out_gemm<<<dim3(8, 8, 4), 256, 0, stream>>>(CTh, CTl, W_O, out);
}

// Round 4
// 367.162 us; speedup vs baseline: 3.7988x; 1.0173x over previous
//
#include <hip/hip_runtime.h>
#include <hip/hip_bf16.h>
#include <math.h>

#define B_ 4
#define S_ 1024
#define E_ 1024
#define H_ 16
#define D_ 64

typedef __attribute__((ext_vector_type(8))) short   s16x8;
typedef __attribute__((ext_vector_type(8))) unsigned short u16x8;
typedef __attribute__((ext_vector_type(4))) unsigned short u16x4;
typedef __attribute__((ext_vector_type(4))) float   f32x4;
typedef unsigned short u16;

__device__ __forceinline__ u16 f2bf(float f) {
    union { float f; unsigned u; } v; v.f = f;
    unsigned u = v.u + 0x7FFFu + ((v.u >> 16) & 1u);
    return (u16)(u >> 16);
}
__device__ __forceinline__ float bf2f(u16 h) {
    union { unsigned u; float f; } v; v.u = ((unsigned)h) << 16;
    return v.f;
}
__device__ __forceinline__ void splitf(float f, u16& h, u16& l) {
    h = f2bf(f);
    l = f2bf(f - bf2f(h));
}

#define MFMA(a, b, c) __builtin_amdgcn_mfma_f32_16x16x32_bf16((a), (b), (c), 0, 0, 0)

#define LDR 40   // qkv/out LDS row stride (32 data + 8 pad)

// ---------------------------------------------------------------------------
// Kernel 1: QKV projection GEMM (bf16 hi/lo x3).
// Outputs pre-split bf16 hi/lo: q,k as [b,h,s,d] (q pre-scaled by 0.125),
// v transposed [b,h,d,s]. For q,k the MFMA operand order is swapped so the
// accumulator's register-contiguous direction is d -> coalesced u16x4 stores.
// ---------------------------------------------------------------------------
__global__ __launch_bounds__(256) void qkv_gemm(
    const float* __restrict__ x,
    const float* __restrict__ Wq, const float* __restrict__ Wk, const float* __restrict__ Wv,
    u16* __restrict__ qh, u16* __restrict__ ql,
    u16* __restrict__ kh, u16* __restrict__ kl,
    u16* __restrict__ vth, u16* __restrict__ vtl)
{
    __shared__ __align__(16) u16 Ah[128][LDR], Al[128][LDR], Bh[128][LDR], Bl[128][LDR];

    const int tid  = threadIdx.x;
    const int m0   = blockIdx.x * 128;          // (b,s) rows
    const int n0   = blockIdx.y * 128;          // (w,h,d) cols
    const int w    = n0 >> 10;
    const int h0   = (n0 & 1023) >> 6;
    const float* W = (w == 0) ? Wq : (w == 1) ? Wk : Wv;

    const int wid  = tid >> 6, lane = tid & 63;
    const int wr   = wid >> 1, wc = wid & 1;
    const int lrow = lane & 15, lk = lane >> 4;

    const int sr = tid >> 1;            // A row 0..127
    const int sh = (tid & 1) * 16;      // A k-half
    const int bn = tid & 127;           // B n 0..127
    const int bk = (tid >> 7) * 16;     // B k-half

    f32x4 acc[4][4] = {};

    for (int k0 = 0; k0 < E_; k0 += 32) {
        __syncthreads();
        // ---- stage A: X rows, fp32 -> hi/lo split (16 elems/thread)
        {
            const float* xp = x + (size_t)(m0 + sr) * E_ + k0 + sh;
            f32x4 a0 = *(const f32x4*)(xp);
            f32x4 a1 = *(const f32x4*)(xp + 4);
            f32x4 a2 = *(const f32x4*)(xp + 8);
            f32x4 a3 = *(const f32x4*)(xp + 12);
            u16x8 h0v, l0v, h1v, l1v;
            #pragma unroll
            for (int j = 0; j < 4; j++) {
                u16 hh, ll;
                splitf(a0[j], hh, ll); h0v[j]     = hh; l0v[j]     = ll;
                splitf(a1[j], hh, ll); h0v[j + 4] = hh; l0v[j + 4] = ll;
                splitf(a2[j], hh, ll); h1v[j]     = hh; l1v[j]     = ll;
                splitf(a3[j], hh, ll); h1v[j + 4] = hh; l1v[j + 4] = ll;
            }
            *(u16x8*)&Ah[sr][sh]     = h0v;  *(u16x8*)&Al[sr][sh]     = l0v;
            *(u16x8*)&Ah[sr][sh + 8] = h1v;  *(u16x8*)&Al[sr][sh + 8] = l1v;
        }
        // ---- stage B: W gather (transpose to n-major)
        {
            const int nh = h0 + (bn >> 6);
            const int nd = bn & 63;
            const float* wp = W + ((size_t)nh * E_ + k0 + bk) * D_ + nd;
            float fb[16];
            #pragma unroll
            for (int i = 0; i < 16; i++) fb[i] = wp[(size_t)i * D_];
            u16x8 h0v, l0v, h1v, l1v;
            #pragma unroll
            for (int j = 0; j < 8; j++) {
                u16 hh, ll;
                splitf(fb[j], hh, ll);     h0v[j] = hh; l0v[j] = ll;
                splitf(fb[j + 8], hh, ll); h1v[j] = hh; l1v[j] = ll;
            }
            *(u16x8*)&Bh[bn][bk]     = h0v;  *(u16x8*)&Bl[bn][bk]     = l0v;
            *(u16x8*)&Bh[bn][bk + 8] = h1v;  *(u16x8*)&Bl[bn][bk + 8] = l1v;
        }
        __syncthreads();

        s16x8 fXh[4], fXl[4], fWh[4], fWl[4];
        #pragma unroll
        for (int i = 0; i < 4; i++) {
            fXh[i] = *(const s16x8*)&Ah[wr * 64 + i * 16 + lrow][lk * 8];
            fXl[i] = *(const s16x8*)&Al[wr * 64 + i * 16 + lrow][lk * 8];
            fWh[i] = *(const s16x8*)&Bh[wc * 64 + i * 16 + lrow][lk * 8];
            fWl[i] = *(const s16x8*)&Bl[wc * 64 + i * 16 + lrow][lk * 8];
        }
        if (w < 2) {
            #pragma unroll
            for (int i = 0; i < 4; i++)
                #pragma unroll
                for (int j = 0; j < 4; j++) {
                    acc[i][j] = MFMA(fWh[i], fXh[j], acc[i][j]);
                    acc[i][j] = MFMA(fWl[i], fXh[j], acc[i][j]);
                    acc[i][j] = MFMA(fWh[i], fXl[j], acc[i][j]);
                }
        } else {
            #pragma unroll
            for (int i = 0; i < 4; i++)
                #pragma unroll
                for (int j = 0; j < 4; j++) {
                    acc[i][j] = MFMA(fXh[i], fWh[j], acc[i][j]);
                    acc[i][j] = MFMA(fXl[i], fWh[j], acc[i][j]);
                    acc[i][j] = MFMA(fXh[i], fWl[j], acc[i][j]);
                }
        }
    }

    const int nloc = n0 & 1023;
    if (w < 2) {
        // acc[i][j]: i = W-frag (n-dim, wc), j = X-frag (m-dim, wr); regs run along d
        u16* Yh = (w == 0) ? qh : kh;
        u16* Yl = (w == 0) ? ql : kl;
        const float sc = (w == 0) ? 0.125f : 1.0f;
        #pragma unroll
        for (int i = 0; i < 4; i++) {
            const int nn = nloc + wc * 64 + i * 16 + lk * 4;
            const int hh2 = nn >> 6, d0 = nn & 63;
            #pragma unroll
            for (int j = 0; j < 4; j++) {
                const int mrow = m0 + wr * 64 + j * 16 + lrow;
                const int b = mrow >> 10, s = mrow & 1023;
                u16x4 oh, ol;
                #pragma unroll
                for (int r = 0; r < 4; r++) {
                    u16 hhv, llv;
                    splitf(acc[i][j][r] * sc, hhv, llv);
                    oh[r] = hhv; ol[r] = llv;
                }
                const size_t off = (((size_t)b * H_ + hh2) * S_ + s) * D_ + d0;
                *(u16x4*)(Yh + off) = oh;
                *(u16x4*)(Yl + off) = ol;
            }
        }
    } else {
        // acc[i][j]: i = X-frag (m-dim, wr), j = W-frag (n-dim, wc); regs run along s
        #pragma unroll
        for (int i = 0; i < 4; i++) {
            const int mrow = m0 + wr * 64 + i * 16 + lk * 4;
            const int b = mrow >> 10, s = mrow & 1023;
            #pragma unroll
            for (int j = 0; j < 4; j++) {
                const int nn = nloc + wc * 64 + j * 16 + lrow;
                const int hh2 = nn >> 6, d0 = nn & 63;
                u16x4 oh, ol;
                #pragma unroll
                for (int r = 0; r < 4; r++) {
                    u16 hhv, llv;
                    splitf(acc[i][j][r], hhv, llv);
                    oh[r] = hhv; ol[r] = llv;
                }
                const size_t off = (((size_t)b * H_ + hh2) * D_ + d0) * S_ + s;
                *(u16x4*)(vth + off) = oh;
                *(u16x4*)(vtl + off) = ol;
            }
        }
    }
}

// ---------------------------------------------------------------------------
// Kernel 2: causal flash attention, pre-split inputs, KVBLK=64.
// 4 waves x 16 q-rows; 2 barriers/tile (P is per-wave, no barrier needed).
// ---------------------------------------------------------------------------
__global__ __launch_bounds__(256) void attn(
    const u16* __restrict__ qh, const u16* __restrict__ ql,
    const u16* __restrict__ kh, const u16* __restrict__ kl,
    const u16* __restrict__ vth, const u16* __restrict__ vtl,
    u16* __restrict__ CTh, u16* __restrict__ CTl)
{
    const int qt = 15 - blockIdx.x;     // heavy blocks first
    const int bh = blockIdx.y;

    __shared__ __align__(16) u16 Kh[64][72], Kl[64][72];
    __shared__ __align__(16) u16 Vh[64][72], Vl[64][72];
    __shared__ __align__(16) u16 Ph[4][16][72], Pl[4][16][72];

    const int tid = threadIdx.x, wid = tid >> 6, lane = tid & 63;
    const int lrow = lane & 15, lk = lane >> 4;
    const int q0g = qt * 64 + wid * 16;

    // Q fragments (pre-scaled, pre-split)
    s16x8 fQh[2], fQl[2];
    {
        const size_t qoff = ((size_t)bh * S_ + q0g + lrow) * D_;
        #pragma unroll
        for (int ks = 0; ks < 2; ks++) {
            fQh[ks] = *(const s16x8*)(qh + qoff + ks * 32 + lk * 8);
            fQl[ks] = *(const s16x8*)(ql + qoff + ks * 32 + lk * 8);
        }
    }

    f32x4 accO[4] = {};
    float m_r[4], l_r[4];
    #pragma unroll
    for (int r = 0; r < 4; r++) { m_r[r] = -INFINITY; l_r[r] = 0.0f; }

    const u16* Kbh = kh  + (size_t)bh * S_ * D_;
    const u16* Kbl = kl  + (size_t)bh * S_ * D_;
    const u16* Vbh = vth + (size_t)bh * D_ * S_;
    const u16* Vbl = vtl + (size_t)bh * D_ * S_;

    const int rk = tid >> 2, ck = (tid & 3) * 16;

    for (int t = 0; t <= qt; t++) {
        const int c0 = t * 64;
        __syncthreads();          // all waves done reading K/V of prev tile
        // ---- stage K [sk 64][d 64] and V [d 64][sk 64] (pure copies)
        {
            const size_t ko = (size_t)(c0 + rk) * D_ + ck;
            *(u16x8*)&Kh[rk][ck]     = *(const u16x8*)(Kbh + ko);
            *(u16x8*)&Kh[rk][ck + 8] = *(const u16x8*)(Kbh + ko + 8);
            *(u16x8*)&Kl[rk][ck]     = *(const u16x8*)(Kbl + ko);
            *(u16x8*)&Kl[rk][ck + 8] = *(const u16x8*)(Kbl + ko + 8);
            const size_t vo = (size_t)rk * S_ + c0 + ck;
            *(u16x8*)&Vh[rk][ck]     = *(const u16x8*)(Vbh + vo);
            *(u16x8*)&Vh[rk][ck + 8] = *(const u16x8*)(Vbh + vo + 8);
            *(u16x8*)&Vl[rk][ck]     = *(const u16x8*)(Vbl + vo);
            *(u16x8*)&Vl[rk][ck + 8] = *(const u16x8*)(Vbl + vo + 8);
        }
        __syncthreads();

        // ---- QK^T: S[16 sq][64 sk]
        f32x4 accS[4] = {};
        __builtin_amdgcn_s_setprio(1);
        #pragma unroll
        for (int nf = 0; nf < 4; nf++) {
            #pragma unroll
            for (int ks = 0; ks < 2; ks++) {
                const s16x8 kfh = *(const s16x8*)&Kh[nf * 16 + lrow][ks * 32 + lk * 8];
                const s16x8 kfl = *(const s16x8*)&Kl[nf * 16 + lrow][ks * 32 + lk * 8];
                accS[nf] = MFMA(fQh[ks], kfh, accS[nf]);
                accS[nf] = MFMA(fQl[ks], kfh, accS[nf]);
                accS[nf] = MFMA(fQh[ks], kfl, accS[nf]);
            }
        }
        __builtin_amdgcn_s_setprio(0);

        // ---- causal mask (diagonal tile only)
        if (c0 + 63 > q0g) {
            #pragma unroll
            for (int nf = 0; nf < 4; nf++)
                #pragma unroll
                for (int r = 0; r < 4; r++) {
                    if (c0 + nf * 16 + lrow > q0g + lk * 4 + r) accS[nf][r] = -INFINITY;
                }
        }

        // ---- online softmax (row sq = lk*4+r, reduce over 16-lane group)
        float rs[4];
        #pragma unroll
        for (int r = 0; r < 4; r++) {
            float v = fmaxf(fmaxf(accS[0][r], accS[1][r]), fmaxf(accS[2][r], accS[3][r]));
            #pragma unroll
            for (int d_ = 1; d_ < 16; d_ <<= 1) v = fmaxf(v, __shfl_xor(v, d_));
            const float mnew = fmaxf(m_r[r], v);
            rs[r] = __expf(m_r[r] - mnew);
            m_r[r] = mnew;
            float sum = 0.0f;
            #pragma unroll
            for (int nf = 0; nf < 4; nf++) {
                const float p = __expf(accS[nf][r] - mnew);
                accS[nf][r] = p;
                sum += p;
            }
            #pragma unroll
            for (int d_ = 1; d_ < 16; d_ <<= 1) sum += __shfl_xor(sum, d_);
            l_r[r] = l_r[r] * rs[r] + sum;
        }

        // ---- write P (per-wave slice; no barrier needed)
        #pragma unroll
        for (int nf = 0; nf < 4; nf++)
            #pragma unroll
            for (int r = 0; r < 4; r++) {
                u16 hh, ll;
                splitf(accS[nf][r], hh, ll);
                Ph[wid][lk * 4 + r][nf * 16 + lrow] = hh;
                Pl[wid][lk * 4 + r][nf * 16 + lrow] = ll;
            }
        // ---- rescale O
        #pragma unroll
        for (int df = 0; df < 4; df++)
            #pragma unroll
            for (int r = 0; r < 4; r++) accO[df][r] *= rs[r];

        // ---- PV
        s16x8 fPh[2], fPl[2];
        #pragma unroll
        for (int ks = 0; ks < 2; ks++) {
            fPh[ks] = *(const s16x8*)&Ph[wid][lrow][ks * 32 + lk * 8];
            fPl[ks] = *(const s16x8*)&Pl[wid][lrow][ks * 32 + lk * 8];
        }
        __builtin_amdgcn_s_setprio(1);
        #pragma unroll
        for (int df = 0; df < 4; df++) {
            #pragma unroll
            for (int ks = 0; ks < 2; ks++) {
                const s16x8 vfh = *(const s16x8*)&Vh[df * 16 + lrow][ks * 32 + lk * 8];
                const s16x8 vfl = *(const s16x8*)&Vl[df * 16 + lrow][ks * 32 + lk * 8];
                accO[df] = MFMA(fPh[ks], vfh, accO[df]);
                accO[df] = MFMA(fPl[ks], vfh, accO[df]);
                accO[df] = MFMA(fPh[ks], vfl, accO[df]);
            }
        }
        __builtin_amdgcn_s_setprio(0);
    }

    // ---- epilogue: normalize, write concatT hi/lo (s-contiguous)
    const int b = bh >> 4, h = bh & 15;
    float inv[4];
    #pragma unroll
    for (int r = 0; r < 4; r++) inv[r] = 1.0f / l_r[r];
    #pragma unroll
    for (int df = 0; df < 4; df++) {
        const int e = h * 64 + df * 16 + lrow;
        const int s = q0g + lk * 4;
        u16x4 oh, ol;
        #pragma unroll
        for (int r = 0; r < 4; r++) {
            u16 hh, ll;
            splitf(accO[df][r] * inv[r], hh, ll);
            oh[r] = hh; ol[r] = ll;
        }
        const size_t off = ((size_t)b * E_ + e) * S_ + s;
        *(u16x4*)(CTh + off) = oh;
        *(u16x4*)(CTl + off) = ol;
    }
}

// ---------------------------------------------------------------------------
// Kernel 3: output GEMM.  out[b][i][j] = sum_s WO[i][s] * C[b][s][j]
// D[m=j][n=i] = sum_s CT[j][s] * WO[i][s]; A = CT (pre-split), B = WO (split).
// ---------------------------------------------------------------------------
__global__ __launch_bounds__(256) void out_gemm(
    const u16* __restrict__ CTh, const u16* __restrict__ CTl,
    const float* __restrict__ WO, float* __restrict__ out)
{
    __shared__ __align__(16) u16 Ah[128][LDR], Al[128][LDR], Bh[128][LDR], Bl[128][LDR];

    const int tid = threadIdx.x;
    const int j0 = blockIdx.x * 128;
    const int i0 = blockIdx.y * 128;
    const int b  = blockIdx.z;

    const int wid = tid >> 6, lane = tid & 63;
    const int wr = wid >> 1, wc = wid & 1;
    const int lrow = lane & 15, lk = lane >> 4;

    const int sr = tid >> 1;
    const int sh = (tid & 1) * 16;

    f32x4 acc[4][4] = {};

    for (int k0 = 0; k0 < S_; k0 += 32) {
        __syncthreads();
        // ---- stage A: CT rows (pre-split), 16 elems/thread
        {
            const size_t off = ((size_t)b * E_ + j0 + sr) * S_ + k0 + sh;
            *(u16x8*)&Ah[sr][sh]     = *(const u16x8*)(CTh + off);
            *(u16x8*)&Ah[sr][sh + 8] = *(const u16x8*)(CTh + off + 8);
            *(u16x8*)&Al[sr][sh]     = *(const u16x8*)(CTl + off);
            *(u16x8*)&Al[sr][sh + 8] = *(const u16x8*)(CTl + off + 8);
        }
        // ---- stage B: WO rows fp32 -> split
        {
            const float* wp = WO + (size_t)(i0 + sr) * S_ + k0 + sh;
            f32x4 a0 = *(const f32x4*)(wp);
            f32x4 a1 = *(const f32x4*)(wp + 4);
            f32x4 a2 = *(const f32x4*)(wp + 8);
            f32x4 a3 = *(const f32x4*)(wp + 12);
            u16x8 h0v, l0v, h1v, l1v;
            #pragma unroll
            for (int j = 0; j < 4; j++) {
                u16 hh, ll;
                splitf(a0[j], hh, ll); h0v[j]     = hh; l0v[j]     = ll;
                splitf(a1[j], hh, ll); h0v[j + 4] = hh; l0v[j + 4] = ll;
                splitf(a2[j], hh, ll); h1v[j]     = hh; l1v[j]     = ll;
                splitf(a3[j], hh, ll); h1v[j + 4] = hh; l1v[j + 4] = ll;
            }
            *(u16x8*)&Bh[sr][sh]     = h0v;  *(u16x8*)&Bl[sr][sh]     = l0v;
            *(u16x8*)&Bh[sr][sh + 8] = h1v;  *(u16x8*)&Bl[sr][sh + 8] = l1v;
        }
        __syncthreads();

        s16x8 fAh[4], fAl[4], fBh[4], fBl[4];
        #pragma unroll
        for (int i = 0; i < 4; i++) {
            fAh[i] = *(const s16x8*)&Ah[wr * 64 + i * 16 + lrow][lk * 8];
            fAl[i] = *(const s16x8*)&Al[wr * 64 + i * 16 + lrow][lk * 8];
            fBh[i] = *(const s16x8*)&Bh[wc * 64 + i * 16 + lrow][lk * 8];
            fBl[i] = *(const s16x8*)&Bl[wc * 64 + i * 16 + lrow][lk * 8];
        }
        #pragma unroll
        for (int i = 0; i < 4; i++)
            #pragma unroll
            for (int j = 0; j < 4; j++) {
                acc[i][j] = MFMA(fAh[i], fBh[j], acc[i][j]);
                acc[i][j] = MFMA(fAl[i], fBh[j], acc[i][j]);
                acc[i][j] = MFMA(fAh[i], fBl[j], acc[i][j]);
            }
    }

    #pragma unroll
    for (int i = 0; i < 4; i++) {
        const int jj = j0 + wr * 64 + i * 16 + lk * 4;
        #pragma unroll
        for (int j = 0; j < 4; j++) {
            const int ii = i0 + wc * 64 + j * 16 + lrow;
            float* dst = out + ((size_t)b * E_ + ii) * E_ + jj;
            *(f32x4*)dst = acc[i][j];
        }
    }
}

// ---------------------------------------------------------------------------
extern "C" void kernel_launch(void* const* d_in, const int* in_sizes, int n_in,
                              void* d_out, int out_size, void* d_ws, size_t ws_size,
                              hipStream_t stream)
{
    const float* x   = (const float*)d_in[0];
    const float* Wq  = (const float*)d_in[1];
    const float* Wk  = (const float*)d_in[2];
    const float* Wv  = (const float*)d_in[3];
    const float* W_O = (const float*)d_in[4];
    float* out = (float*)d_out;

    const size_t N = (size_t)B_ * H_ * S_ * D_;   // 4,194,304
    u16* ws16 = (u16*)d_ws;
    u16* qh  = ws16;
    u16* ql  = qh  + N;
    u16* kh  = ql  + N;
    u16* kl  = kh  + N;
    u16* vth = kl  + N;
    u16* vtl = vth + N;
    u16* CTh = vtl + N;
    u16* CTl = CTh + N;

    qkv_gemm<<<dim3(32, 24), 256, 0, stream>>>(x, Wq, Wk, Wv, qh, ql, kh, kl, vth, vtl);
    attn<<<dim3(16, 64), 256, 0, stream>>>(qh, ql, kh, kl, vth, vtl, CTh, CTl);
    out_gemm<<<dim3(8, 8, 4), 256, 0, stream>>>(CTh, CTl, W_O, out);
}

// Round 7
// 348.956 us; speedup vs baseline: 3.9970x; 1.0522x over previous
//
#include <hip/hip_runtime.h>
#include <hip/hip_bf16.h>
#include <math.h>

#define B_ 4
#define S_ 1024
#define E_ 1024
#define H_ 16
#define D_ 64

typedef __attribute__((ext_vector_type(8))) short   s16x8;
typedef __attribute__((ext_vector_type(8))) unsigned short u16x8;
typedef __attribute__((ext_vector_type(4))) unsigned short u16x4;
typedef __attribute__((ext_vector_type(4))) float   f32x4;
typedef unsigned short u16;

__device__ __forceinline__ u16 f2bf(float f) {
    union { float f; unsigned u; } v; v.f = f;
    unsigned u = v.u + 0x7FFFu + ((v.u >> 16) & 1u);
    return (u16)(u >> 16);
}
__device__ __forceinline__ float bf2f(u16 h) {
    union { unsigned u; float f; } v; v.u = ((unsigned)h) << 16;
    return v.f;
}
__device__ __forceinline__ void splitf(float f, u16& h, u16& l) {
    h = f2bf(f);
    l = f2bf(f - bf2f(h));
}

#define MFMA(a, b, c) __builtin_amdgcn_mfma_f32_16x16x32_bf16((a), (b), (c), 0, 0, 0)

#define LDR 40   // LDS row stride (32 data + 8 pad)

// ---------------------------------------------------------------------------
// Prep A: elementwise fp32 -> bf16 hi/lo split (8 elems/thread, exact-size grid)
// ---------------------------------------------------------------------------
__global__ __launch_bounds__(256) void split_f32(
    const float* __restrict__ src, u16* __restrict__ h, u16* __restrict__ l)
{
    const size_t i = ((size_t)blockIdx.x * 256 + threadIdx.x) * 8;
    f32x4 a = *(const f32x4*)(src + i);
    f32x4 b = *(const f32x4*)(src + i + 4);
    u16x8 hv, lv;
    #pragma unroll
    for (int j = 0; j < 4; j++) {
        u16 hh, ll;
        splitf(a[j], hh, ll); hv[j]     = hh; lv[j]     = ll;
        splitf(b[j], hh, ll); hv[j + 4] = hh; lv[j + 4] = ll;
    }
    *(u16x8*)(h + i) = hv;
    *(u16x8*)(l + i) = lv;
}

// ---------------------------------------------------------------------------
// Prep B: W[h][e][d] fp32 -> Wt[n = w*1024 + h*64 + d][e] bf16 hi/lo (transpose)
// One block = 64(e) x 64(d) tile, LDS-transposed, both sides coalesced.
// ---------------------------------------------------------------------------
__global__ __launch_bounds__(256) void split_wT(
    const float* __restrict__ Wq, const float* __restrict__ Wk, const float* __restrict__ Wv,
    u16* __restrict__ wth, u16* __restrict__ wtl)
{
    __shared__ float T[64][65];
    const int e0 = blockIdx.x * 64;
    const int h  = blockIdx.y;
    const int w  = blockIdx.z;
    const float* W = (w == 0) ? Wq : (w == 1) ? Wk : Wv;

    const int tid = threadIdx.x;
    const int r4  = tid >> 4;          // 0..15
    const int c4  = (tid & 15) * 4;    // 0,4,..,60

    #pragma unroll
    for (int p = 0; p < 4; p++) {
        const int r = p * 16 + r4;     // e within tile
        f32x4 v = *(const f32x4*)(W + ((size_t)h * E_ + e0 + r) * D_ + c4);
        #pragma unroll
        for (int j = 0; j < 4; j++) T[r][c4 + j] = v[j];
    }
    __syncthreads();
    #pragma unroll
    for (int p = 0; p < 4; p++) {
        const int d = p * 16 + r4;     // d within tile
        u16x4 oh, ol;
        #pragma unroll
        for (int j = 0; j < 4; j++) {
            u16 hh, ll;
            splitf(T[c4 + j][d], hh, ll);
            oh[j] = hh; ol[j] = ll;
        }
        const size_t n   = (size_t)w * 1024 + h * 64 + d;
        const size_t off = n * E_ + e0 + c4;
        *(u16x4*)(wth + off) = oh;
        *(u16x4*)(wtl + off) = ol;
    }
}

// ---------------------------------------------------------------------------
// Kernel 1: QKV projection GEMM, pre-split A (xh/xl) and B (wth/wtl).
// Staging is pure u16x8 copies. MFMA bf16 hi/lo x3. Outputs pre-split:
// q,k [b,h,s,d] (q pre-scaled 0.125), v transposed [b,h,d,s].
// ---------------------------------------------------------------------------
__global__ __launch_bounds__(256) void qkv_gemm(
    const u16* __restrict__ xh, const u16* __restrict__ xl,
    const u16* __restrict__ wth, const u16* __restrict__ wtl,
    u16* __restrict__ qh, u16* __restrict__ ql,
    u16* __restrict__ kh, u16* __restrict__ kl,
    u16* __restrict__ vth, u16* __restrict__ vtl)
{
    __shared__ __align__(16) u16 Ah[128][LDR], Al[128][LDR], Bh[128][LDR], Bl[128][LDR];

    const int tid = threadIdx.x;
    const int m0  = blockIdx.x * 128;          // (b,s) rows
    const int n0  = blockIdx.y * 128;          // (w,h,d) cols
    const int w   = n0 >> 10;

    const int wid  = tid >> 6, lane = tid & 63;
    const int wr   = wid >> 1, wc = wid & 1;
    const int lrow = lane & 15, lk = lane >> 4;

    const int sr = tid >> 1;            // row 0..127
    const int sh = (tid & 1) * 16;      // k-half

    f32x4 acc[4][4] = {};

    for (int k0 = 0; k0 < E_; k0 += 32) {
        __syncthreads();
        {
            const size_t ao = (size_t)(m0 + sr) * E_ + k0 + sh;
            *(u16x8*)&Ah[sr][sh]     = *(const u16x8*)(xh + ao);
            *(u16x8*)&Ah[sr][sh + 8] = *(const u16x8*)(xh + ao + 8);
            *(u16x8*)&Al[sr][sh]     = *(const u16x8*)(xl + ao);
            *(u16x8*)&Al[sr][sh + 8] = *(const u16x8*)(xl + ao + 8);
            const size_t bo = (size_t)(n0 + sr) * E_ + k0 + sh;
            *(u16x8*)&Bh[sr][sh]     = *(const u16x8*)(wth + bo);
            *(u16x8*)&Bh[sr][sh + 8] = *(const u16x8*)(wth + bo + 8);
            *(u16x8*)&Bl[sr][sh]     = *(const u16x8*)(wtl + bo);
            *(u16x8*)&Bl[sr][sh + 8] = *(const u16x8*)(wtl + bo + 8);
        }
        __syncthreads();

        s16x8 fXh[4], fXl[4], fWh[4], fWl[4];
        #pragma unroll
        for (int i = 0; i < 4; i++) {
            fXh[i] = *(const s16x8*)&Ah[wr * 64 + i * 16 + lrow][lk * 8];
            fXl[i] = *(const s16x8*)&Al[wr * 64 + i * 16 + lrow][lk * 8];
            fWh[i] = *(const s16x8*)&Bh[wc * 64 + i * 16 + lrow][lk * 8];
            fWl[i] = *(const s16x8*)&Bl[wc * 64 + i * 16 + lrow][lk * 8];
        }
        __builtin_amdgcn_s_setprio(1);
        if (w < 2) {
            #pragma unroll
            for (int i = 0; i < 4; i++)
                #pragma unroll
                for (int j = 0; j < 4; j++) {
                    acc[i][j] = MFMA(fWh[i], fXh[j], acc[i][j]);
                    acc[i][j] = MFMA(fWl[i], fXh[j], acc[i][j]);
                    acc[i][j] = MFMA(fWh[i], fXl[j], acc[i][j]);
                }
        } else {
            #pragma unroll
            for (int i = 0; i < 4; i++)
                #pragma unroll
                for (int j = 0; j < 4; j++) {
                    acc[i][j] = MFMA(fXh[i], fWh[j], acc[i][j]);
                    acc[i][j] = MFMA(fXl[i], fWh[j], acc[i][j]);
                    acc[i][j] = MFMA(fXh[i], fWl[j], acc[i][j]);
                }
        }
        __builtin_amdgcn_s_setprio(0);
    }

    const int nloc = n0 & 1023;
    if (w < 2) {
        // acc[i][j]: i = W-frag (n-dim), j = X-frag (m-dim); regs run along d
        u16* Yh = (w == 0) ? qh : kh;
        u16* Yl = (w == 0) ? ql : kl;
        const float sc = (w == 0) ? 0.125f : 1.0f;
        #pragma unroll
        for (int i = 0; i < 4; i++) {
            const int nn = nloc + wc * 64 + i * 16 + lk * 4;
            const int hh2 = nn >> 6, d0 = nn & 63;
            #pragma unroll
            for (int j = 0; j < 4; j++) {
                const int mrow = m0 + wr * 64 + j * 16 + lrow;
                const int b = mrow >> 10, s = mrow & 1023;
                u16x4 oh, ol;
                #pragma unroll
                for (int r = 0; r < 4; r++) {
                    u16 hhv, llv;
                    splitf(acc[i][j][r] * sc, hhv, llv);
                    oh[r] = hhv; ol[r] = llv;
                }
                const size_t off = (((size_t)b * H_ + hh2) * S_ + s) * D_ + d0;
                *(u16x4*)(Yh + off) = oh;
                *(u16x4*)(Yl + off) = ol;
            }
        }
    } else {
        // acc[i][j]: i = X-frag (m-dim), j = W-frag (n-dim); regs run along s
        #pragma unroll
        for (int i = 0; i < 4; i++) {
            const int mrow = m0 + wr * 64 + i * 16 + lk * 4;
            const int b = mrow >> 10, s = mrow & 1023;
            #pragma unroll
            for (int j = 0; j < 4; j++) {
                const int nn = nloc + wc * 64 + j * 16 + lrow;
                const int hh2 = nn >> 6, d0 = nn & 63;
                u16x4 oh, ol;
                #pragma unroll
                for (int r = 0; r < 4; r++) {
                    u16 hhv, llv;
                    splitf(acc[i][j][r], hhv, llv);
                    oh[r] = hhv; ol[r] = llv;
                }
                const size_t off = (((size_t)b * H_ + hh2) * D_ + d0) * S_ + s;
                *(u16x4*)(vth + off) = oh;
                *(u16x4*)(vtl + off) = ol;
            }
        }
    }
}

// ---------------------------------------------------------------------------
// Kernel 2: causal flash attention, pre-split inputs, KVBLK=64,
// T14 async-stage: next tile's K/V loads issued at compute start (regs).
// ---------------------------------------------------------------------------
__global__ __launch_bounds__(256) void attn(
    const u16* __restrict__ qh, const u16* __restrict__ ql,
    const u16* __restrict__ kh, const u16* __restrict__ kl,
    const u16* __restrict__ vth, const u16* __restrict__ vtl,
    u16* __restrict__ CTh, u16* __restrict__ CTl)
{
    const int qt = 15 - blockIdx.x;     // heavy blocks first
    const int bh = blockIdx.y;

    __shared__ __align__(16) u16 Kh[64][72], Kl[64][72];
    __shared__ __align__(16) u16 Vh[64][72], Vl[64][72];
    __shared__ __align__(16) u16 Ph[4][16][72], Pl[4][16][72];

    const int tid = threadIdx.x, wid = tid >> 6, lane = tid & 63;
    const int lrow = lane & 15, lk = lane >> 4;
    const int q0g = qt * 64 + wid * 16;

    s16x8 fQh[2], fQl[2];
    {
        const size_t qoff = ((size_t)bh * S_ + q0g + lrow) * D_;
        #pragma unroll
        for (int ks = 0; ks < 2; ks++) {
            fQh[ks] = *(const s16x8*)(qh + qoff + ks * 32 + lk * 8);
            fQl[ks] = *(const s16x8*)(ql + qoff + ks * 32 + lk * 8);
        }
    }

    f32x4 accO[4] = {};
    float m_r[4], l_r[4];
    #pragma unroll
    for (int r = 0; r < 4; r++) { m_r[r] = -INFINITY; l_r[r] = 0.0f; }

    const u16* Kbh = kh  + (size_t)bh * S_ * D_;
    const u16* Kbl = kl  + (size_t)bh * S_ * D_;
    const u16* Vbh = vth + (size_t)bh * D_ * S_;
    const u16* Vbl = vtl + (size_t)bh * D_ * S_;

    const int rk = tid >> 2, ck = (tid & 3) * 16;

    u16x8 pf0, pf1, pf2, pf3, pf4, pf5, pf6, pf7;
#define ISSUE(c0_) { \
        const size_t ko = (size_t)((c0_) + rk) * D_ + ck; \
        pf0 = *(const u16x8*)(Kbh + ko);     pf1 = *(const u16x8*)(Kbh + ko + 8); \
        pf2 = *(const u16x8*)(Kbl + ko);     pf3 = *(const u16x8*)(Kbl + ko + 8); \
        const size_t vo = (size_t)rk * S_ + (c0_) + ck; \
        pf4 = *(const u16x8*)(Vbh + vo);     pf5 = *(const u16x8*)(Vbh + vo + 8); \
        pf6 = *(const u16x8*)(Vbl + vo);     pf7 = *(const u16x8*)(Vbl + vo + 8); }

    ISSUE(0)

    for (int t = 0; t <= qt; t++) {
        const int c0 = t * 64;
        __syncthreads();          // all waves done reading K/V of prev tile
        *(u16x8*)&Kh[rk][ck]     = pf0;  *(u16x8*)&Kh[rk][ck + 8] = pf1;
        *(u16x8*)&Kl[rk][ck]     = pf2;  *(u16x8*)&Kl[rk][ck + 8] = pf3;
        *(u16x8*)&Vh[rk][ck]     = pf4;  *(u16x8*)&Vh[rk][ck + 8] = pf5;
        *(u16x8*)&Vl[rk][ck]     = pf6;  *(u16x8*)&Vl[rk][ck + 8] = pf7;
        __syncthreads();

        if (t < qt) ISSUE(c0 + 64)      // in flight during compute below

        // ---- QK^T: S[16 sq][64 sk]
        f32x4 accS[4] = {};
        __builtin_amdgcn_s_setprio(1);
        #pragma unroll
        for (int nf = 0; nf < 4; nf++) {
            #pragma unroll
            for (int ks = 0; ks < 2; ks++) {
                const s16x8 kfh = *(const s16x8*)&Kh[nf * 16 + lrow][ks * 32 + lk * 8];
                const s16x8 kfl = *(const s16x8*)&Kl[nf * 16 + lrow][ks * 32 + lk * 8];
                accS[nf] = MFMA(fQh[ks], kfh, accS[nf]);
                accS[nf] = MFMA(fQl[ks], kfh, accS[nf]);
                accS[nf] = MFMA(fQh[ks], kfl, accS[nf]);
            }
        }
        __builtin_amdgcn_s_setprio(0);

        // ---- causal mask (diagonal tile only)
        if (c0 + 63 > q0g) {
            #pragma unroll
            for (int nf = 0; nf < 4; nf++)
                #pragma unroll
                for (int r = 0; r < 4; r++) {
                    if (c0 + nf * 16 + lrow > q0g + lk * 4 + r) accS[nf][r] = -INFINITY;
                }
        }

        // ---- online softmax
        float rs[4];
        #pragma unroll
        for (int r = 0; r < 4; r++) {
            float v = fmaxf(fmaxf(accS[0][r], accS[1][r]), fmaxf(accS[2][r], accS[3][r]));
            #pragma unroll
            for (int d_ = 1; d_ < 16; d_ <<= 1) v = fmaxf(v, __shfl_xor(v, d_));
            const float mnew = fmaxf(m_r[r], v);
            rs[r] = __expf(m_r[r] - mnew);
            m_r[r] = mnew;
            float sum = 0.0f;
            #pragma unroll
            for (int nf = 0; nf < 4; nf++) {
                const float p = __expf(accS[nf][r] - mnew);
                accS[nf][r] = p;
                sum += p;
            }
            #pragma unroll
            for (int d_ = 1; d_ < 16; d_ <<= 1) sum += __shfl_xor(sum, d_);
            l_r[r] = l_r[r] * rs[r] + sum;
        }

        // ---- write P (per-wave slice; no barrier needed)
        #pragma unroll
        for (int nf = 0; nf < 4; nf++)
            #pragma unroll
            for (int r = 0; r < 4; r++) {
                u16 hh, ll;
                splitf(accS[nf][r], hh, ll);
                Ph[wid][lk * 4 + r][nf * 16 + lrow] = hh;
                Pl[wid][lk * 4 + r][nf * 16 + lrow] = ll;
            }
        // ---- rescale O
        #pragma unroll
        for (int df = 0; df < 4; df++)
            #pragma unroll
            for (int r = 0; r < 4; r++) accO[df][r] *= rs[r];

        // ---- PV
        s16x8 fPh[2], fPl[2];
        #pragma unroll
        for (int ks = 0; ks < 2; ks++) {
            fPh[ks] = *(const s16x8*)&Ph[wid][lrow][ks * 32 + lk * 8];
            fPl[ks] = *(const s16x8*)&Pl[wid][lrow][ks * 32 + lk * 8];
        }
        __builtin_amdgcn_s_setprio(1);
        #pragma unroll
        for (int df = 0; df < 4; df++) {
            #pragma unroll
            for (int ks = 0; ks < 2; ks++) {
                const s16x8 vfh = *(const s16x8*)&Vh[df * 16 + lrow][ks * 32 + lk * 8];
                const s16x8 vfl = *(const s16x8*)&Vl[df * 16 + lrow][ks * 32 + lk * 8];
                accO[df] = MFMA(fPh[ks], vfh, accO[df]);
                accO[df] = MFMA(fPl[ks], vfh, accO[df]);
                accO[df] = MFMA(fPh[ks], vfl, accO[df]);
            }
        }
        __builtin_amdgcn_s_setprio(0);
    }
#undef ISSUE

    // ---- epilogue: normalize, write concatT hi/lo (s-contiguous)
    const int b = bh >> 4, h = bh & 15;
    float inv[4];
    #pragma unroll
    for (int r = 0; r < 4; r++) inv[r] = 1.0f / l_r[r];
    #pragma unroll
    for (int df = 0; df < 4; df++) {
        const int e = h * 64 + df * 16 + lrow;
        const int s = q0g + lk * 4;
        u16x4 oh, ol;
        #pragma unroll
        for (int r = 0; r < 4; r++) {
            u16 hh, ll;
            splitf(accO[df][r] * inv[r], hh, ll);
            oh[r] = hh; ol[r] = ll;
        }
        const size_t off = ((size_t)b * E_ + e) * S_ + s;
        *(u16x4*)(CTh + off) = oh;
        *(u16x4*)(CTl + off) = ol;
    }
}

// ---------------------------------------------------------------------------
// Kernel 3: output GEMM.  out[b][i][j] = sum_s WO[i][s] * C[b][s][j]
// D[m=j][n=i] = sum_s CT[j][s] * WO[i][s]; all staging pre-split copies.
// ---------------------------------------------------------------------------
__global__ __launch_bounds__(256) void out_gemm(
    const u16* __restrict__ CTh, const u16* __restrict__ CTl,
    const u16* __restrict__ woh, const u16* __restrict__ wol,
    float* __restrict__ out)
{
    __shared__ __align__(16) u16 Ah[128][LDR], Al[128][LDR], Bh[128][LDR], Bl[128][LDR];

    const int tid = threadIdx.x;
    const int j0 = blockIdx.x * 128;
    const int i0 = blockIdx.y * 128;
    const int b  = blockIdx.z;

    const int wid = tid >> 6, lane = tid & 63;
    const int wr = wid >> 1, wc = wid & 1;
    const int lrow = lane & 15, lk = lane >> 4;

    const int sr = tid >> 1;
    const int sh = (tid & 1) * 16;

    f32x4 acc[4][4] = {};

    for (int k0 = 0; k0 < S_; k0 += 32) {
        __syncthreads();
        {
            const size_t ao = ((size_t)b * E_ + j0 + sr) * S_ + k0 + sh;
            *(u16x8*)&Ah[sr][sh]     = *(const u16x8*)(CTh + ao);
            *(u16x8*)&Ah[sr][sh + 8] = *(const u16x8*)(CTh + ao + 8);
            *(u16x8*)&Al[sr][sh]     = *(const u16x8*)(CTl + ao);
            *(u16x8*)&Al[sr][sh + 8] = *(const u16x8*)(CTl + ao + 8);
            const size_t bo = (size_t)(i0 + sr) * S_ + k0 + sh;
            *(u16x8*)&Bh[sr][sh]     = *(const u16x8*)(woh + bo);
            *(u16x8*)&Bh[sr][sh + 8] = *(const u16x8*)(woh + bo + 8);
            *(u16x8*)&Bl[sr][sh]     = *(const u16x8*)(wol + bo);
            *(u16x8*)&Bl[sr][sh + 8] = *(const u16x8*)(wol + bo + 8);
        }
        __syncthreads();

        s16x8 fAh[4], fAl[4], fBh[4], fBl[4];
        #pragma unroll
        for (int i = 0; i < 4; i++) {
            fAh[i] = *(const s16x8*)&Ah[wr * 64 + i * 16 + lrow][lk * 8];
            fAl[i] = *(const s16x8*)&Al[wr * 64 + i * 16 + lrow][lk * 8];
            fBh[i] = *(const s16x8*)&Bh[wc * 64 + i * 16 + lrow][lk * 8];
            fBl[i] = *(const s16x8*)&Bl[wc * 64 + i * 16 + lrow][lk * 8];
        }
        __builtin_amdgcn_s_setprio(1);
        #pragma unroll
        for (int i = 0; i < 4; i++)
            #pragma unroll
            for (int j = 0; j < 4; j++) {
                acc[i][j] = MFMA(fAh[i], fBh[j], acc[i][j]);
                acc[i][j] = MFMA(fAl[i], fBh[j], acc[i][j]);
                acc[i][j] = MFMA(fAh[i], fBl[j], acc[i][j]);
            }
        __builtin_amdgcn_s_setprio(0);
    }

    #pragma unroll
    for (int i = 0; i < 4; i++) {
        const int jj = j0 + wr * 64 + i * 16 + lk * 4;
        #pragma unroll
        for (int j = 0; j < 4; j++) {
            const int ii = i0 + wc * 64 + j * 16 + lrow;
            float* dst = out + ((size_t)b * E_ + ii) * E_ + jj;
            *(f32x4*)dst = acc[i][j];
        }
    }
}

// ---------------------------------------------------------------------------
extern "C" void kernel_launch(void* const* d_in, const int* in_sizes, int n_in,
                              void* d_out, int out_size, void* d_ws, size_t ws_size,
                              hipStream_t stream)
{
    const float* x   = (const float*)d_in[0];
    const float* Wq  = (const float*)d_in[1];
    const float* Wk  = (const float*)d_in[2];
    const float* Wv  = (const float*)d_in[3];
    const float* W_O = (const float*)d_in[4];
    float* out = (float*)d_out;

    const size_t N = (size_t)B_ * S_ * E_;   // 4,194,304
    u16* p = (u16*)d_ws;
    u16* qh  = p;            u16* ql  = p + 1 * N;
    u16* kh  = p + 2 * N;    u16* kl  = p + 3 * N;
    u16* vth = p + 4 * N;    u16* vtl = p + 5 * N;
    u16* xh  = p + 6 * N;    u16* xl  = p + 7 * N;    // reused as CTh/CTl
    u16* wth = p + 8 * N;                             // 3*E*E u16
    u16* wtl = wth + (size_t)3 * E_ * E_;
    u16* CTh = xh;           u16* CTl = xl;           // alias (x dead after qkv)
    u16* woh = wth;          u16* wol = wtl;          // alias (Wt dead after qkv)

    split_f32<<<2048, 256, 0, stream>>>(x, xh, xl);
    split_wT<<<dim3(16, 16, 3), 256, 0, stream>>>(Wq, Wk, Wv, wth, wtl);
    qkv_gemm<<<dim3(32, 24), 256, 0, stream>>>(xh, xl, wth, wtl, qh, ql, kh, kl, vth, vtl);
    split_f32<<<512, 256, 0, stream>>>(W_O, woh, wol);
    attn<<<dim3(16, 64), 256, 0, stream>>>(qh, ql, kh, kl, vth, vtl, CTh, CTl);
    out_gemm<<<dim3(8, 8, 4), 256, 0, stream>>>(CTh, CTl, woh, wol, out);
}

// Round 8
// 329.346 us; speedup vs baseline: 4.2350x; 1.0595x over previous
//
#include <hip/hip_runtime.h>
#include <hip/hip_bf16.h>
#include <math.h>

#define B_ 4
#define S_ 1024
#define E_ 1024
#define H_ 16
#define D_ 64

typedef __attribute__((ext_vector_type(8))) short   s16x8;
typedef __attribute__((ext_vector_type(8))) unsigned short u16x8;
typedef __attribute__((ext_vector_type(4))) unsigned short u16x4;
typedef __attribute__((ext_vector_type(4))) float   f32x4;
typedef unsigned short u16;

__device__ __forceinline__ u16 f2bf(float f) {
    union { float f; unsigned u; } v; v.f = f;
    unsigned u = v.u + 0x7FFFu + ((v.u >> 16) & 1u);
    return (u16)(u >> 16);
}
__device__ __forceinline__ float bf2f(u16 h) {
    union { unsigned u; float f; } v; v.u = ((unsigned)h) << 16;
    return v.f;
}
__device__ __forceinline__ void splitf(float f, u16& h, u16& l) {
    h = f2bf(f);
    l = f2bf(f - bf2f(h));
}

#define MFMA(a, b, c) __builtin_amdgcn_mfma_f32_16x16x32_bf16((a), (b), (c), 0, 0, 0)

// async global->LDS, 16B per lane; dest = wave-uniform base + lane*16
__device__ __forceinline__ void gload16(const u16* g, u16* l) {
    __builtin_amdgcn_global_load_lds(
        (const __attribute__((address_space(1))) void*)g,
        (__attribute__((address_space(3))) void*)l, 16, 0, 0);
}

// tiled operand layout: [blk][kstep][row 128][col 32] u16, tile = 4096 elems (8KB)
#define TILE_E   4096
#define BLK_E    131072   // 32 ksteps * 4096

// ---------------------------------------------------------------------------
// Prep: fp32 [rows][1024] -> hi/lo bf16 in tiled layout.
// Works for x (4096 rows, grid 2048) and W_O (1024 rows, grid 512).
// ---------------------------------------------------------------------------
__global__ __launch_bounds__(256) void tile_rows(
    const float* __restrict__ src, u16* __restrict__ th, u16* __restrict__ tl)
{
    const size_t i = ((size_t)blockIdx.x * 256 + threadIdx.x) * 8;
    const int m = (int)(i >> 10), e = (int)(i & 1023);
    f32x4 a = *(const f32x4*)(src + i);
    f32x4 b = *(const f32x4*)(src + i + 4);
    u16x8 hv, lv;
    #pragma unroll
    for (int j = 0; j < 4; j++) {
        u16 hh, ll;
        splitf(a[j], hh, ll); hv[j]     = hh; lv[j]     = ll;
        splitf(b[j], hh, ll); hv[j + 4] = hh; lv[j + 4] = ll;
    }
    const int mblk = m >> 7, row = m & 127, ks = e >> 5, col = e & 31;
    const size_t off = ((size_t)(mblk * 32 + ks) * 128 + row) * 32 + col;
    *(u16x8*)(th + off) = hv;
    *(u16x8*)(tl + off) = lv;
}

// ---------------------------------------------------------------------------
// Prep: W[h][e][d] fp32 -> transposed n-major tiled hi/lo.
// n = w*1024 + h*64 + d; tiled [n>>7][e>>5][n&127][e&31].
// ---------------------------------------------------------------------------
__global__ __launch_bounds__(256) void tile_w(
    const float* __restrict__ Wq, const float* __restrict__ Wk, const float* __restrict__ Wv,
    u16* __restrict__ wth, u16* __restrict__ wtl)
{
    __shared__ float T[64][65];
    const int e0 = blockIdx.x * 64;
    const int h  = blockIdx.y;
    const int w  = blockIdx.z;
    const float* W = (w == 0) ? Wq : (w == 1) ? Wk : Wv;

    const int tid = threadIdx.x;
    const int r4  = tid >> 4;          // 0..15
    const int c4  = (tid & 15) * 4;    // 0,4,..,60

    #pragma unroll
    for (int p = 0; p < 4; p++) {
        const int r = p * 16 + r4;     // e within tile
        f32x4 v = *(const f32x4*)(W + ((size_t)h * E_ + e0 + r) * D_ + c4);
        #pragma unroll
        for (int j = 0; j < 4; j++) T[r][c4 + j] = v[j];
    }
    __syncthreads();
    const int nblk = w * 8 + (h >> 1);
    const int ks   = (e0 + c4) >> 5;
    const int col  = (e0 + c4) & 31;
    #pragma unroll
    for (int p = 0; p < 4; p++) {
        const int d = p * 16 + r4;
        u16x4 oh, ol;
        #pragma unroll
        for (int j = 0; j < 4; j++) {
            u16 hh, ll;
            splitf(T[c4 + j][d], hh, ll);
            oh[j] = hh; ol[j] = ll;
        }
        const int row = (h & 1) * 64 + d;
        const size_t off = ((size_t)(nblk * 32 + ks) * 128 + row) * 32 + col;
        *(u16x4*)(wth + off) = oh;
        *(u16x4*)(wtl + off) = ol;
    }
}

// ---------------------------------------------------------------------------
// Kernel 1: QKV projection GEMM; staging via global_load_lds (tiled operands).
// Outputs pre-split: q,k [b,h,s,d] (q pre-scaled 0.125), v transposed [b,h,d,s].
// ---------------------------------------------------------------------------
__global__ __launch_bounds__(256) void qkv_gemm(
    const u16* __restrict__ xsh, const u16* __restrict__ xsl,
    const u16* __restrict__ wth, const u16* __restrict__ wtl,
    u16* __restrict__ qh, u16* __restrict__ ql,
    u16* __restrict__ kh, u16* __restrict__ kl,
    u16* __restrict__ vth, u16* __restrict__ vtl)
{
    __shared__ __align__(16) u16 Ah[128][32], Al[128][32], Bh[128][32], Bl[128][32];

    const int tid  = threadIdx.x;
    const int mblk = blockIdx.x;               // 0..31 over (b,s)
    const int nblk = blockIdx.y;               // 0..23 over (w,h,d)
    const int n0   = nblk * 128;
    const int w    = n0 >> 10;

    const int wid  = tid >> 6, lane = tid & 63;
    const int wr   = wid >> 1, wc = wid & 1;
    const int lrow = lane & 15, lk = lane >> 4;

    // per-wave staging assignment
    const u16* gsrc;
    u16* lbase;
    if      (wid == 0) { gsrc = xsh + (size_t)mblk * BLK_E; lbase = &Ah[0][0]; }
    else if (wid == 1) { gsrc = xsl + (size_t)mblk * BLK_E; lbase = &Al[0][0]; }
    else if (wid == 2) { gsrc = wth + (size_t)nblk * BLK_E; lbase = &Bh[0][0]; }
    else               { gsrc = wtl + (size_t)nblk * BLK_E; lbase = &Bl[0][0]; }

    f32x4 acc[4][4] = {};

    for (int ks = 0; ks < 32; ks++) {
        __syncthreads();                       // readers of prev tile done
        {
            const u16* s = gsrc + (size_t)ks * TILE_E + lane * 8;
            u16* l = lbase + lane * 8;
            #pragma unroll
            for (int c = 0; c < 8; c++)
                gload16(s + c * 512, l + c * 512);
        }
        __syncthreads();                       // vmcnt(0) drain -> data visible

        s16x8 fXh[4], fXl[4], fWh[4], fWl[4];
        #pragma unroll
        for (int i = 0; i < 4; i++) {
            fXh[i] = *(const s16x8*)&Ah[wr * 64 + i * 16 + lrow][lk * 8];
            fXl[i] = *(const s16x8*)&Al[wr * 64 + i * 16 + lrow][lk * 8];
            fWh[i] = *(const s16x8*)&Bh[wc * 64 + i * 16 + lrow][lk * 8];
            fWl[i] = *(const s16x8*)&Bl[wc * 64 + i * 16 + lrow][lk * 8];
        }
        __builtin_amdgcn_s_setprio(1);
        if (w < 2) {
            #pragma unroll
            for (int i = 0; i < 4; i++)
                #pragma unroll
                for (int j = 0; j < 4; j++) {
                    acc[i][j] = MFMA(fWh[i], fXh[j], acc[i][j]);
                    acc[i][j] = MFMA(fWl[i], fXh[j], acc[i][j]);
                    acc[i][j] = MFMA(fWh[i], fXl[j], acc[i][j]);
                }
        } else {
            #pragma unroll
            for (int i = 0; i < 4; i++)
                #pragma unroll
                for (int j = 0; j < 4; j++) {
                    acc[i][j] = MFMA(fXh[i], fWh[j], acc[i][j]);
                    acc[i][j] = MFMA(fXl[i], fWh[j], acc[i][j]);
                    acc[i][j] = MFMA(fXh[i], fWl[j], acc[i][j]);
                }
        }
        __builtin_amdgcn_s_setprio(0);
    }

    const int m0   = mblk * 128;
    const int nloc = n0 & 1023;
    if (w < 2) {
        // acc[i][j]: i = W-frag (n-dim), j = X-frag (m-dim); regs run along d
        u16* Yh = (w == 0) ? qh : kh;
        u16* Yl = (w == 0) ? ql : kl;
        const float sc = (w == 0) ? 0.125f : 1.0f;
        #pragma unroll
        for (int i = 0; i < 4; i++) {
            const int nn = nloc + wc * 64 + i * 16 + lk * 4;
            const int hh2 = nn >> 6, d0 = nn & 63;
            #pragma unroll
            for (int j = 0; j < 4; j++) {
                const int mrow = m0 + wr * 64 + j * 16 + lrow;
                const int b = mrow >> 10, s = mrow & 1023;
                u16x4 oh, ol;
                #pragma unroll
                for (int r = 0; r < 4; r++) {
                    u16 hhv, llv;
                    splitf(acc[i][j][r] * sc, hhv, llv);
                    oh[r] = hhv; ol[r] = llv;
                }
                const size_t off = (((size_t)b * H_ + hh2) * S_ + s) * D_ + d0;
                *(u16x4*)(Yh + off) = oh;
                *(u16x4*)(Yl + off) = ol;
            }
        }
    } else {
        // acc[i][j]: i = X-frag (m-dim), j = W-frag (n-dim); regs run along s
        #pragma unroll
        for (int i = 0; i < 4; i++) {
            const int mrow = m0 + wr * 64 + i * 16 + lk * 4;
            const int b = mrow >> 10, s = mrow & 1023;
            #pragma unroll
            for (int j = 0; j < 4; j++) {
                const int nn = nloc + wc * 64 + j * 16 + lrow;
                const int hh2 = nn >> 6, d0 = nn & 63;
                u16x4 oh, ol;
                #pragma unroll
                for (int r = 0; r < 4; r++) {
                    u16 hhv, llv;
                    splitf(acc[i][j][r], hhv, llv);
                    oh[r] = hhv; ol[r] = llv;
                }
                const size_t off = (((size_t)b * H_ + hh2) * D_ + d0) * S_ + s;
                *(u16x4*)(vth + off) = oh;
                *(u16x4*)(vtl + off) = ol;
            }
        }
    }
}

// ---------------------------------------------------------------------------
// Kernel 2: causal flash attention (unchanged structure), CT written TILED:
// per b: [e>>7][s>>5][e&127][s&31] hi/lo.
// ---------------------------------------------------------------------------
__global__ __launch_bounds__(256) void attn(
    const u16* __restrict__ qh, const u16* __restrict__ ql,
    const u16* __restrict__ kh, const u16* __restrict__ kl,
    const u16* __restrict__ vth, const u16* __restrict__ vtl,
    u16* __restrict__ CTh, u16* __restrict__ CTl)
{
    const int qt = 15 - blockIdx.x;     // heavy blocks first
    const int bh = blockIdx.y;

    __shared__ __align__(16) u16 Kh[64][72], Kl[64][72];
    __shared__ __align__(16) u16 Vh[64][72], Vl[64][72];
    __shared__ __align__(16) u16 Ph[4][16][72], Pl[4][16][72];

    const int tid = threadIdx.x, wid = tid >> 6, lane = tid & 63;
    const int lrow = lane & 15, lk = lane >> 4;
    const int q0g = qt * 64 + wid * 16;

    s16x8 fQh[2], fQl[2];
    {
        const size_t qoff = ((size_t)bh * S_ + q0g + lrow) * D_;
        #pragma unroll
        for (int ks = 0; ks < 2; ks++) {
            fQh[ks] = *(const s16x8*)(qh + qoff + ks * 32 + lk * 8);
            fQl[ks] = *(const s16x8*)(ql + qoff + ks * 32 + lk * 8);
        }
    }

    f32x4 accO[4] = {};
    float m_r[4], l_r[4];
    #pragma unroll
    for (int r = 0; r < 4; r++) { m_r[r] = -INFINITY; l_r[r] = 0.0f; }

    const u16* Kbh = kh  + (size_t)bh * S_ * D_;
    const u16* Kbl = kl  + (size_t)bh * S_ * D_;
    const u16* Vbh = vth + (size_t)bh * D_ * S_;
    const u16* Vbl = vtl + (size_t)bh * D_ * S_;

    const int rk = tid >> 2, ck = (tid & 3) * 16;

    u16x8 pf0, pf1, pf2, pf3, pf4, pf5, pf6, pf7;
#define ISSUE(c0_) { \
        const size_t ko = (size_t)((c0_) + rk) * D_ + ck; \
        pf0 = *(const u16x8*)(Kbh + ko);     pf1 = *(const u16x8*)(Kbh + ko + 8); \
        pf2 = *(const u16x8*)(Kbl + ko);     pf3 = *(const u16x8*)(Kbl + ko + 8); \
        const size_t vo = (size_t)rk * S_ + (c0_) + ck; \
        pf4 = *(const u16x8*)(Vbh + vo);     pf5 = *(const u16x8*)(Vbh + vo + 8); \
        pf6 = *(const u16x8*)(Vbl + vo);     pf7 = *(const u16x8*)(Vbl + vo + 8); }

    ISSUE(0)

    for (int t = 0; t <= qt; t++) {
        const int c0 = t * 64;
        __syncthreads();
        *(u16x8*)&Kh[rk][ck]     = pf0;  *(u16x8*)&Kh[rk][ck + 8] = pf1;
        *(u16x8*)&Kl[rk][ck]     = pf2;  *(u16x8*)&Kl[rk][ck + 8] = pf3;
        *(u16x8*)&Vh[rk][ck]     = pf4;  *(u16x8*)&Vh[rk][ck + 8] = pf5;
        *(u16x8*)&Vl[rk][ck]     = pf6;  *(u16x8*)&Vl[rk][ck + 8] = pf7;
        __syncthreads();

        if (t < qt) ISSUE(c0 + 64)

        // ---- QK^T
        f32x4 accS[4] = {};
        __builtin_amdgcn_s_setprio(1);
        #pragma unroll
        for (int nf = 0; nf < 4; nf++) {
            #pragma unroll
            for (int ks = 0; ks < 2; ks++) {
                const s16x8 kfh = *(const s16x8*)&Kh[nf * 16 + lrow][ks * 32 + lk * 8];
                const s16x8 kfl = *(const s16x8*)&Kl[nf * 16 + lrow][ks * 32 + lk * 8];
                accS[nf] = MFMA(fQh[ks], kfh, accS[nf]);
                accS[nf] = MFMA(fQl[ks], kfh, accS[nf]);
                accS[nf] = MFMA(fQh[ks], kfl, accS[nf]);
            }
        }
        __builtin_amdgcn_s_setprio(0);

        // ---- causal mask (diagonal tile only)
        if (c0 + 63 > q0g) {
            #pragma unroll
            for (int nf = 0; nf < 4; nf++)
                #pragma unroll
                for (int r = 0; r < 4; r++) {
                    if (c0 + nf * 16 + lrow > q0g + lk * 4 + r) accS[nf][r] = -INFINITY;
                }
        }

        // ---- online softmax
        float rs[4];
        #pragma unroll
        for (int r = 0; r < 4; r++) {
            float v = fmaxf(fmaxf(accS[0][r], accS[1][r]), fmaxf(accS[2][r], accS[3][r]));
            #pragma unroll
            for (int d_ = 1; d_ < 16; d_ <<= 1) v = fmaxf(v, __shfl_xor(v, d_));
            const float mnew = fmaxf(m_r[r], v);
            rs[r] = __expf(m_r[r] - mnew);
            m_r[r] = mnew;
            float sum = 0.0f;
            #pragma unroll
            for (int nf = 0; nf < 4; nf++) {
                const float p = __expf(accS[nf][r] - mnew);
                accS[nf][r] = p;
                sum += p;
            }
            #pragma unroll
            for (int d_ = 1; d_ < 16; d_ <<= 1) sum += __shfl_xor(sum, d_);
            l_r[r] = l_r[r] * rs[r] + sum;
        }

        // ---- write P (per-wave slice; no barrier needed)
        #pragma unroll
        for (int nf = 0; nf < 4; nf++)
            #pragma unroll
            for (int r = 0; r < 4; r++) {
                u16 hh, ll;
                splitf(accS[nf][r], hh, ll);
                Ph[wid][lk * 4 + r][nf * 16 + lrow] = hh;
                Pl[wid][lk * 4 + r][nf * 16 + lrow] = ll;
            }
        // ---- rescale O
        #pragma unroll
        for (int df = 0; df < 4; df++)
            #pragma unroll
            for (int r = 0; r < 4; r++) accO[df][r] *= rs[r];

        // ---- PV
        s16x8 fPh[2], fPl[2];
        #pragma unroll
        for (int ks = 0; ks < 2; ks++) {
            fPh[ks] = *(const s16x8*)&Ph[wid][lrow][ks * 32 + lk * 8];
            fPl[ks] = *(const s16x8*)&Pl[wid][lrow][ks * 32 + lk * 8];
        }
        __builtin_amdgcn_s_setprio(1);
        #pragma unroll
        for (int df = 0; df < 4; df++) {
            #pragma unroll
            for (int ks = 0; ks < 2; ks++) {
                const s16x8 vfh = *(const s16x8*)&Vh[df * 16 + lrow][ks * 32 + lk * 8];
                const s16x8 vfl = *(const s16x8*)&Vl[df * 16 + lrow][ks * 32 + lk * 8];
                accO[df] = MFMA(fPh[ks], vfh, accO[df]);
                accO[df] = MFMA(fPl[ks], vfh, accO[df]);
                accO[df] = MFMA(fPh[ks], vfl, accO[df]);
            }
        }
        __builtin_amdgcn_s_setprio(0);
    }
#undef ISSUE

    // ---- epilogue: normalize, write CT TILED hi/lo
    const int b = bh >> 4, h = bh & 15;
    float inv[4];
    #pragma unroll
    for (int r = 0; r < 4; r++) inv[r] = 1.0f / l_r[r];
    const int s0 = q0g + lk * 4;
    const int kst = s0 >> 5, col = s0 & 31;
    #pragma unroll
    for (int df = 0; df < 4; df++) {
        const int e = h * 64 + df * 16 + lrow;
        const int jblk = e >> 7, row = e & 127;
        u16x4 oh, ol;
        #pragma unroll
        for (int r = 0; r < 4; r++) {
            u16 hh, ll;
            splitf(accO[df][r] * inv[r], hh, ll);
            oh[r] = hh; ol[r] = ll;
        }
        const size_t off = (size_t)b * 1048576 +
                           ((size_t)(jblk * 32 + kst) * 128 + row) * 32 + col;
        *(u16x4*)(CTh + off) = oh;
        *(u16x4*)(CTl + off) = ol;
    }
}

// ---------------------------------------------------------------------------
// Kernel 3: output GEMM via global_load_lds (tiled CT and tiled W_O).
// D[m=j][n=i] = sum_s CT[j][s] * WO[i][s].
// ---------------------------------------------------------------------------
__global__ __launch_bounds__(256) void out_gemm(
    const u16* __restrict__ CTh, const u16* __restrict__ CTl,
    const u16* __restrict__ woh, const u16* __restrict__ wol,
    float* __restrict__ out)
{
    __shared__ __align__(16) u16 Ah[128][32], Al[128][32], Bh[128][32], Bl[128][32];

    const int tid  = threadIdx.x;
    const int jblk = blockIdx.x;          // CT rows (j = e of concat)
    const int iblk = blockIdx.y;          // WO rows (i)
    const int b    = blockIdx.z;

    const int wid = tid >> 6, lane = tid & 63;
    const int wr = wid >> 1, wc = wid & 1;
    const int lrow = lane & 15, lk = lane >> 4;

    const u16* gsrc;
    u16* lbase;
    if      (wid == 0) { gsrc = CTh + (size_t)b * 1048576 + (size_t)jblk * BLK_E; lbase = &Ah[0][0]; }
    else if (wid == 1) { gsrc = CTl + (size_t)b * 1048576 + (size_t)jblk * BLK_E; lbase = &Al[0][0]; }
    else if (wid == 2) { gsrc = woh + (size_t)iblk * BLK_E; lbase = &Bh[0][0]; }
    else               { gsrc = wol + (size_t)iblk * BLK_E; lbase = &Bl[0][0]; }

    f32x4 acc[4][4] = {};

    for (int ks = 0; ks < 32; ks++) {
        __syncthreads();
        {
            const u16* s = gsrc + (size_t)ks * TILE_E + lane * 8;
            u16* l = lbase + lane * 8;
            #pragma unroll
            for (int c = 0; c < 8; c++)
                gload16(s + c * 512, l + c * 512);
        }
        __syncthreads();

        s16x8 fAh[4], fAl[4], fBh[4], fBl[4];
        #pragma unroll
        for (int i = 0; i < 4; i++) {
            fAh[i] = *(const s16x8*)&Ah[wr * 64 + i * 16 + lrow][lk * 8];
            fAl[i] = *(const s16x8*)&Al[wr * 64 + i * 16 + lrow][lk * 8];
            fBh[i] = *(const s16x8*)&Bh[wc * 64 + i * 16 + lrow][lk * 8];
            fBl[i] = *(const s16x8*)&Bl[wc * 64 + i * 16 + lrow][lk * 8];
        }
        __builtin_amdgcn_s_setprio(1);
        #pragma unroll
        for (int i = 0; i < 4; i++)
            #pragma unroll
            for (int j = 0; j < 4; j++) {
                acc[i][j] = MFMA(fAh[i], fBh[j], acc[i][j]);
                acc[i][j] = MFMA(fAl[i], fBh[j], acc[i][j]);
                acc[i][j] = MFMA(fAh[i], fBl[j], acc[i][j]);
            }
        __builtin_amdgcn_s_setprio(0);
    }

    const int j0 = jblk * 128, i0 = iblk * 128;
    #pragma unroll
    for (int i = 0; i < 4; i++) {
        const int jj = j0 + wr * 64 + i * 16 + lk * 4;
        #pragma unroll
        for (int j = 0; j < 4; j++) {
            const int ii = i0 + wc * 64 + j * 16 + lrow;
            float* dst = out + ((size_t)b * E_ + ii) * E_ + jj;
            *(f32x4*)dst = acc[i][j];
        }
    }
}

// ---------------------------------------------------------------------------
extern "C" void kernel_launch(void* const* d_in, const int* in_sizes, int n_in,
                              void* d_out, int out_size, void* d_ws, size_t ws_size,
                              hipStream_t stream)
{
    const float* x   = (const float*)d_in[0];
    const float* Wq  = (const float*)d_in[1];
    const float* Wk  = (const float*)d_in[2];
    const float* Wv  = (const float*)d_in[3];
    const float* W_O = (const float*)d_in[4];
    float* out = (float*)d_out;

    const size_t N = (size_t)B_ * S_ * E_;   // 4,194,304
    u16* p = (u16*)d_ws;
    u16* qh  = p;            u16* ql  = p + 1 * N;
    u16* kh  = p + 2 * N;    u16* kl  = p + 3 * N;
    u16* vth = p + 4 * N;    u16* vtl = p + 5 * N;
    u16* xsh = p + 6 * N;    u16* xsl = p + 7 * N;    // tiled x; reused as CT
    u16* wth = p + 8 * N;                             // tiled W (3*E*E u16)
    u16* wtl = wth + (size_t)3 * E_ * E_;
    u16* CTh = xsh;          u16* CTl = xsl;          // alias (x dead after qkv)
    u16* woh = wth;          u16* wol = wth + (size_t)E_ * E_;  // alias (Wt dead)

    tile_rows<<<2048, 256, 0, stream>>>(x, xsh, xsl);
    tile_w<<<dim3(16, 16, 3), 256, 0, stream>>>(Wq, Wk, Wv, wth, wtl);
    qkv_gemm<<<dim3(32, 24), 256, 0, stream>>>(xsh, xsl, wth, wtl,
                                               qh, ql, kh, kl, vth, vtl);
    tile_rows<<<512, 256, 0, stream>>>(W_O, woh, wol);
    attn<<<dim3(16, 64), 256, 0, stream>>>(qh, ql, kh, kl, vth, vtl, CTh, CTl);
    out_gemm<<<dim3(8, 8, 4), 256, 0, stream>>>(CTh, CTl, woh, wol, out);
}

// Round 10
// 296.640 us; speedup vs baseline: 4.7019x; 1.1103x over previous
//
#include <hip/hip_runtime.h>
#include <hip/hip_bf16.h>
#include <math.h>

#define B_ 4
#define S_ 1024
#define E_ 1024
#define H_ 16
#define D_ 64

typedef __attribute__((ext_vector_type(8))) short   s16x8;
typedef __attribute__((ext_vector_type(8))) unsigned short u16x8;
typedef __attribute__((ext_vector_type(4))) unsigned short u16x4;
typedef __attribute__((ext_vector_type(4))) float   f32x4;
typedef unsigned short u16;

__device__ __forceinline__ u16 f2bf(float f) {
    union { float f; unsigned u; } v; v.f = f;
    unsigned u = v.u + 0x7FFFu + ((v.u >> 16) & 1u);
    return (u16)(u >> 16);
}
__device__ __forceinline__ float bf2f(u16 h) {
    union { unsigned u; float f; } v; v.u = ((unsigned)h) << 16;
    return v.f;
}
__device__ __forceinline__ void splitf(float f, u16& h, u16& l) {
    h = f2bf(f);
    l = f2bf(f - bf2f(h));
}

#define MFMA(a, b, c) __builtin_amdgcn_mfma_f32_16x16x32_bf16((a), (b), (c), 0, 0, 0)

// async global->LDS, 16B per lane; dest = wave-uniform base + lane*16
__device__ __forceinline__ void gload16(const u16* g, u16* l) {
    __builtin_amdgcn_global_load_lds(
        (const __attribute__((address_space(1))) void*)g,
        (__attribute__((address_space(3))) void*)l, 16, 0, 0);
}

// tiled operand layout: [blk][kstep][row 128][col 32] u16, tile = 4096 elems (8KB)
#define TILE_E   4096
#define BLK_E    131072   // 32 ksteps * 4096

// ---------------------------------------------------------------------------
// Prep: fp32 [rows][1024] -> hi/lo bf16 in tiled layout.
// Works for x (4096 rows, grid 2048) and W_O (1024 rows, grid 512).
// ---------------------------------------------------------------------------
__global__ __launch_bounds__(256) void tile_rows(
    const float* __restrict__ src, u16* __restrict__ th, u16* __restrict__ tl)
{
    const size_t i = ((size_t)blockIdx.x * 256 + threadIdx.x) * 8;
    const int m = (int)(i >> 10), e = (int)(i & 1023);
    f32x4 a = *(const f32x4*)(src + i);
    f32x4 b = *(const f32x4*)(src + i + 4);
    u16x8 hv, lv;
    #pragma unroll
    for (int j = 0; j < 4; j++) {
        u16 hh, ll;
        splitf(a[j], hh, ll); hv[j]     = hh; lv[j]     = ll;
        splitf(b[j], hh, ll); hv[j + 4] = hh; lv[j + 4] = ll;
    }
    const int mblk = m >> 7, row = m & 127, ks = e >> 5, col = e & 31;
    const size_t off = ((size_t)(mblk * 32 + ks) * 128 + row) * 32 + col;
    *(u16x8*)(th + off) = hv;
    *(u16x8*)(tl + off) = lv;
}

// ---------------------------------------------------------------------------
// Prep: W[h][e][d] fp32 -> transposed n-major tiled hi/lo.
// n = w*1024 + h*64 + d; tiled [n>>7][e>>5][n&127][e&31].
// ---------------------------------------------------------------------------
__global__ __launch_bounds__(256) void tile_w(
    const float* __restrict__ Wq, const float* __restrict__ Wk, const float* __restrict__ Wv,
    u16* __restrict__ wth, u16* __restrict__ wtl)
{
    __shared__ float T[64][65];
    const int e0 = blockIdx.x * 64;
    const int h  = blockIdx.y;
    const int w  = blockIdx.z;
    const float* W = (w == 0) ? Wq : (w == 1) ? Wk : Wv;

    const int tid = threadIdx.x;
    const int r4  = tid >> 4;          // 0..15
    const int c4  = (tid & 15) * 4;    // 0,4,..,60

    #pragma unroll
    for (int p = 0; p < 4; p++) {
        const int r = p * 16 + r4;     // e within tile
        f32x4 v = *(const f32x4*)(W + ((size_t)h * E_ + e0 + r) * D_ + c4);
        #pragma unroll
        for (int j = 0; j < 4; j++) T[r][c4 + j] = v[j];
    }
    __syncthreads();
    const int nblk = w * 8 + (h >> 1);
    const int ks   = (e0 + c4) >> 5;
    const int col  = (e0 + c4) & 31;
    #pragma unroll
    for (int p = 0; p < 4; p++) {
        const int d = p * 16 + r4;
        u16x4 oh, ol;
        #pragma unroll
        for (int j = 0; j < 4; j++) {
            u16 hh, ll;
            splitf(T[c4 + j][d], hh, ll);
            oh[j] = hh; ol[j] = ll;
        }
        const int row = (h & 1) * 64 + d;
        const size_t off = ((size_t)(nblk * 32 + ks) * 128 + row) * 32 + col;
        *(u16x4*)(wth + off) = oh;
        *(u16x4*)(wtl + off) = ol;
    }
}

// ---------------------------------------------------------------------------
// Kernel 1: QKV projection GEMM; double-buffered global_load_lds pipeline
// (T3-minimum: issue next stage -> compute current -> single barrier).
// Outputs pre-split: q,k [b,h,s,d] (q pre-scaled 0.125), v transposed [b,h,d,s].
// ---------------------------------------------------------------------------
__global__ __launch_bounds__(256) void qkv_gemm(
    const u16* __restrict__ xsh, const u16* __restrict__ xsl,
    const u16* __restrict__ wth, const u16* __restrict__ wtl,
    u16* __restrict__ qh, u16* __restrict__ ql,
    u16* __restrict__ kh, u16* __restrict__ kl,
    u16* __restrict__ vth, u16* __restrict__ vtl)
{
    __shared__ __align__(16) u16 Ah[2][128][32], Al[2][128][32],
                                 Bh[2][128][32], Bl[2][128][32];   // 64 KB

    const int tid  = threadIdx.x;
    const int mblk = blockIdx.x;               // 0..31 over (b,s)
    const int nblk = blockIdx.y;               // 0..23 over (w,h,d)
    const int n0   = nblk * 128;
    const int w    = n0 >> 10;

    const int wid  = tid >> 6, lane = tid & 63;
    const int wr   = wid >> 1, wc = wid & 1;
    const int lrow = lane & 15, lk = lane >> 4;

    // per-wave staging assignment
    const u16* gsrc;
    u16 *lb0, *lb1;
    if      (wid == 0) { gsrc = xsh + (size_t)mblk * BLK_E; lb0 = &Ah[0][0][0]; lb1 = &Ah[1][0][0]; }
    else if (wid == 1) { gsrc = xsl + (size_t)mblk * BLK_E; lb0 = &Al[0][0][0]; lb1 = &Al[1][0][0]; }
    else if (wid == 2) { gsrc = wth + (size_t)nblk * BLK_E; lb0 = &Bh[0][0][0]; lb1 = &Bh[1][0][0]; }
    else               { gsrc = wtl + (size_t)nblk * BLK_E; lb0 = &Bl[0][0][0]; lb1 = &Bl[1][0][0]; }

    f32x4 acc[4][4] = {};

    // prologue: stage k-step 0 into buffer 0
    {
        const u16* s = gsrc + lane * 8;
        u16* l = lb0 + lane * 8;
        #pragma unroll
        for (int c = 0; c < 8; c++) gload16(s + c * 512, l + c * 512);
    }
    __syncthreads();

    int buf = 0;
    for (int ks = 0; ks < 32; ks++) {
        // issue next stage into buf^1 (loads fly during compute below)
        if (ks + 1 < 32) {
            const u16* s = gsrc + (size_t)(ks + 1) * TILE_E + lane * 8;
            u16* l = (buf ? lb0 : lb1) + lane * 8;
            #pragma unroll
            for (int c = 0; c < 8; c++) gload16(s + c * 512, l + c * 512);
        }

        s16x8 fXh[4], fXl[4], fWh[4], fWl[4];
        #pragma unroll
        for (int i = 0; i < 4; i++) {
            fXh[i] = *(const s16x8*)&Ah[buf][wr * 64 + i * 16 + lrow][lk * 8];
            fXl[i] = *(const s16x8*)&Al[buf][wr * 64 + i * 16 + lrow][lk * 8];
            fWh[i] = *(const s16x8*)&Bh[buf][wc * 64 + i * 16 + lrow][lk * 8];
            fWl[i] = *(const s16x8*)&Bl[buf][wc * 64 + i * 16 + lrow][lk * 8];
        }
        __builtin_amdgcn_s_setprio(1);
        if (w < 2) {
            #pragma unroll
            for (int i = 0; i < 4; i++)
                #pragma unroll
                for (int j = 0; j < 4; j++) {
                    acc[i][j] = MFMA(fWh[i], fXh[j], acc[i][j]);
                    acc[i][j] = MFMA(fWl[i], fXh[j], acc[i][j]);
                    acc[i][j] = MFMA(fWh[i], fXl[j], acc[i][j]);
                }
        } else {
            #pragma unroll
            for (int i = 0; i < 4; i++)
                #pragma unroll
                for (int j = 0; j < 4; j++) {
                    acc[i][j] = MFMA(fXh[i], fWh[j], acc[i][j]);
                    acc[i][j] = MFMA(fXl[i], fWh[j], acc[i][j]);
                    acc[i][j] = MFMA(fXh[i], fWl[j], acc[i][j]);
                }
        }
        __builtin_amdgcn_s_setprio(0);
        __syncthreads();      // drains vmcnt(0): next buffer ready; readers done
        buf ^= 1;
    }

    const int m0   = mblk * 128;
    const int nloc = n0 & 1023;
    if (w < 2) {
        // acc[i][j]: i = W-frag (n-dim), j = X-frag (m-dim); regs run along d
        u16* Yh = (w == 0) ? qh : kh;
        u16* Yl = (w == 0) ? ql : kl;
        const float sc = (w == 0) ? 0.125f : 1.0f;
        #pragma unroll
        for (int i = 0; i < 4; i++) {
            const int nn = nloc + wc * 64 + i * 16 + lk * 4;
            const int hh2 = nn >> 6, d0 = nn & 63;
            #pragma unroll
            for (int j = 0; j < 4; j++) {
                const int mrow = m0 + wr * 64 + j * 16 + lrow;
                const int b = mrow >> 10, s = mrow & 1023;
                u16x4 oh, ol;
                #pragma unroll
                for (int r = 0; r < 4; r++) {
                    u16 hhv, llv;
                    splitf(acc[i][j][r] * sc, hhv, llv);
                    oh[r] = hhv; ol[r] = llv;
                }
                const size_t off = (((size_t)b * H_ + hh2) * S_ + s) * D_ + d0;
                *(u16x4*)(Yh + off) = oh;
                *(u16x4*)(Yl + off) = ol;
            }
        }
    } else {
        // acc[i][j]: i = X-frag (m-dim), j = W-frag (n-dim); regs run along s
        #pragma unroll
        for (int i = 0; i < 4; i++) {
            const int mrow = m0 + wr * 64 + i * 16 + lk * 4;
            const int b = mrow >> 10, s = mrow & 1023;
            #pragma unroll
            for (int j = 0; j < 4; j++) {
                const int nn = nloc + wc * 64 + j * 16 + lrow;
                const int hh2 = nn >> 6, d0 = nn & 63;
                u16x4 oh, ol;
                #pragma unroll
                for (int r = 0; r < 4; r++) {
                    u16 hhv, llv;
                    splitf(acc[i][j][r], hhv, llv);
                    oh[r] = hhv; ol[r] = llv;
                }
                const size_t off = (((size_t)b * H_ + hh2) * D_ + d0) * S_ + s;
                *(u16x4*)(vth + off) = oh;
                *(u16x4*)(vtl + off) = ol;
            }
        }
    }
}

// ---------------------------------------------------------------------------
// Kernel 2: causal flash attention (unchanged), CT written TILED:
// per b: [e>>7][s>>5][e&127][s&31] hi/lo.
// ---------------------------------------------------------------------------
__global__ __launch_bounds__(256) void attn(
    const u16* __restrict__ qh, const u16* __restrict__ ql,
    const u16* __restrict__ kh, const u16* __restrict__ kl,
    const u16* __restrict__ vth, const u16* __restrict__ vtl,
    u16* __restrict__ CTh, u16* __restrict__ CTl)
{
    const int qt = 15 - blockIdx.x;     // heavy blocks first
    const int bh = blockIdx.y;

    __shared__ __align__(16) u16 Kh[64][72], Kl[64][72];
    __shared__ __align__(16) u16 Vh[64][72], Vl[64][72];
    __shared__ __align__(16) u16 Ph[4][16][72], Pl[4][16][72];

    const int tid = threadIdx.x, wid = tid >> 6, lane = tid & 63;
    const int lrow = lane & 15, lk = lane >> 4;
    const int q0g = qt * 64 + wid * 16;

    s16x8 fQh[2], fQl[2];
    {
        const size_t qoff = ((size_t)bh * S_ + q0g + lrow) * D_;
        #pragma unroll
        for (int ks = 0; ks < 2; ks++) {
            fQh[ks] = *(const s16x8*)(qh + qoff + ks * 32 + lk * 8);
            fQl[ks] = *(const s16x8*)(ql + qoff + ks * 32 + lk * 8);
        }
    }

    f32x4 accO[4] = {};
    float m_r[4], l_r[4];
    #pragma unroll
    for (int r = 0; r < 4; r++) { m_r[r] = -INFINITY; l_r[r] = 0.0f; }

    const u16* Kbh = kh  + (size_t)bh * S_ * D_;
    const u16* Kbl = kl  + (size_t)bh * S_ * D_;
    const u16* Vbh = vth + (size_t)bh * D_ * S_;
    const u16* Vbl = vtl + (size_t)bh * D_ * S_;

    const int rk = tid >> 2, ck = (tid & 3) * 16;

    u16x8 pf0, pf1, pf2, pf3, pf4, pf5, pf6, pf7;
#define ISSUE(c0_) { \
        const size_t ko = (size_t)((c0_) + rk) * D_ + ck; \
        pf0 = *(const u16x8*)(Kbh + ko);     pf1 = *(const u16x8*)(Kbh + ko + 8); \
        pf2 = *(const u16x8*)(Kbl + ko);     pf3 = *(const u16x8*)(Kbl + ko + 8); \
        const size_t vo = (size_t)rk * S_ + (c0_) + ck; \
        pf4 = *(const u16x8*)(Vbh + vo);     pf5 = *(const u16x8*)(Vbh + vo + 8); \
        pf6 = *(const u16x8*)(Vbl + vo);     pf7 = *(const u16x8*)(Vbl + vo + 8); }

    ISSUE(0)

    for (int t = 0; t <= qt; t++) {
        const int c0 = t * 64;
        __syncthreads();
        *(u16x8*)&Kh[rk][ck]     = pf0;  *(u16x8*)&Kh[rk][ck + 8] = pf1;
        *(u16x8*)&Kl[rk][ck]     = pf2;  *(u16x8*)&Kl[rk][ck + 8] = pf3;
        *(u16x8*)&Vh[rk][ck]     = pf4;  *(u16x8*)&Vh[rk][ck + 8] = pf5;
        *(u16x8*)&Vl[rk][ck]     = pf6;  *(u16x8*)&Vl[rk][ck + 8] = pf7;
        __syncthreads();

        if (t < qt) ISSUE(c0 + 64)

        // ---- QK^T
        f32x4 accS[4] = {};
        __builtin_amdgcn_s_setprio(1);
        #pragma unroll
        for (int nf = 0; nf < 4; nf++) {
            #pragma unroll
            for (int ks = 0; ks < 2; ks++) {
                const s16x8 kfh = *(const s16x8*)&Kh[nf * 16 + lrow][ks * 32 + lk * 8];
                const s16x8 kfl = *(const s16x8*)&Kl[nf * 16 + lrow][ks * 32 + lk * 8];
                accS[nf] = MFMA(fQh[ks], kfh, accS[nf]);
                accS[nf] = MFMA(fQl[ks], kfh, accS[nf]);
                accS[nf] = MFMA(fQh[ks], kfl, accS[nf]);
            }
        }
        __builtin_amdgcn_s_setprio(0);

        // ---- causal mask (diagonal tile only)
        if (c0 + 63 > q0g) {
            #pragma unroll
            for (int nf = 0; nf < 4; nf++)
                #pragma unroll
                for (int r = 0; r < 4; r++) {
                    if (c0 + nf * 16 + lrow > q0g + lk * 4 + r) accS[nf][r] = -INFINITY;
                }
        }

        // ---- online softmax
        float rs[4];
        #pragma unroll
        for (int r = 0; r < 4; r++) {
            float v = fmaxf(fmaxf(accS[0][r], accS[1][r]), fmaxf(accS[2][r], accS[3][r]));
            #pragma unroll
            for (int d_ = 1; d_ < 16; d_ <<= 1) v = fmaxf(v, __shfl_xor(v, d_));
            const float mnew = fmaxf(m_r[r], v);
            rs[r] = __expf(m_r[r] - mnew);
            m_r[r] = mnew;
            float sum = 0.0f;
            #pragma unroll
            for (int nf = 0; nf < 4; nf++) {
                const float p = __expf(accS[nf][r] - mnew);
                accS[nf][r] = p;
                sum += p;
            }
            #pragma unroll
            for (int d_ = 1; d_ < 16; d_ <<= 1) sum += __shfl_xor(sum, d_);
            l_r[r] = l_r[r] * rs[r] + sum;
        }

        // ---- write P (per-wave slice; no barrier needed)
        #pragma unroll
        for (int nf = 0; nf < 4; nf++)
            #pragma unroll
            for (int r = 0; r < 4; r++) {
                u16 hh, ll;
                splitf(accS[nf][r], hh, ll);
                Ph[wid][lk * 4 + r][nf * 16 + lrow] = hh;
                Pl[wid][lk * 4 + r][nf * 16 + lrow] = ll;
            }
        // ---- rescale O
        #pragma unroll
        for (int df = 0; df < 4; df++)
            #pragma unroll
            for (int r = 0; r < 4; r++) accO[df][r] *= rs[r];

        // ---- PV
        s16x8 fPh[2], fPl[2];
        #pragma unroll
        for (int ks = 0; ks < 2; ks++) {
            fPh[ks] = *(const s16x8*)&Ph[wid][lrow][ks * 32 + lk * 8];
            fPl[ks] = *(const s16x8*)&Pl[wid][lrow][ks * 32 + lk * 8];
        }
        __builtin_amdgcn_s_setprio(1);
        #pragma unroll
        for (int df = 0; df < 4; df++) {
            #pragma unroll
            for (int ks = 0; ks < 2; ks++) {
                const s16x8 vfh = *(const s16x8*)&Vh[df * 16 + lrow][ks * 32 + lk * 8];
                const s16x8 vfl = *(const s16x8*)&Vl[df * 16 + lrow][ks * 32 + lk * 8];
                accO[df] = MFMA(fPh[ks], vfh, accO[df]);
                accO[df] = MFMA(fPl[ks], vfh, accO[df]);
                accO[df] = MFMA(fPh[ks], vfl, accO[df]);
            }
        }
        __builtin_amdgcn_s_setprio(0);
    }
#undef ISSUE

    // ---- epilogue: normalize, write CT TILED hi/lo
    const int b = bh >> 4, h = bh & 15;
    float inv[4];
    #pragma unroll
    for (int r = 0; r < 4; r++) inv[r] = 1.0f / l_r[r];
    const int s0 = q0g + lk * 4;
    const int kst = s0 >> 5, col = s0 & 31;
    #pragma unroll
    for (int df = 0; df < 4; df++) {
        const int e = h * 64 + df * 16 + lrow;
        const int jblk = e >> 7, row = e & 127;
        u16x4 oh, ol;
        #pragma unroll
        for (int r = 0; r < 4; r++) {
            u16 hh, ll;
            splitf(accO[df][r] * inv[r], hh, ll);
            oh[r] = hh; ol[r] = ll;
        }
        const size_t off = (size_t)b * 1048576 +
                           ((size_t)(jblk * 32 + kst) * 128 + row) * 32 + col;
        *(u16x4*)(CTh + off) = oh;
        *(u16x4*)(CTl + off) = ol;
    }
}

// ---------------------------------------------------------------------------
// Kernel 3: output GEMM, same double-buffered pipeline.
// D[m=j][n=i] = sum_s CT[j][s] * WO[i][s].
// ---------------------------------------------------------------------------
__global__ __launch_bounds__(256) void out_gemm(
    const u16* __restrict__ CTh, const u16* __restrict__ CTl,
    const u16* __restrict__ woh, const u16* __restrict__ wol,
    float* __restrict__ out)
{
    __shared__ __align__(16) u16 Ah[2][128][32], Al[2][128][32],
                                 Bh[2][128][32], Bl[2][128][32];   // 64 KB

    const int tid  = threadIdx.x;
    const int jblk = blockIdx.x;          // CT rows (j = e of concat)
    const int iblk = blockIdx.y;          // WO rows (i)
    const int b    = blockIdx.z;

    const int wid = tid >> 6, lane = tid & 63;
    const int wr = wid >> 1, wc = wid & 1;
    const int lrow = lane & 15, lk = lane >> 4;

    const u16* gsrc;
    u16 *lb0, *lb1;
    if      (wid == 0) { gsrc = CTh + (size_t)b * 1048576 + (size_t)jblk * BLK_E; lb0 = &Ah[0][0][0]; lb1 = &Ah[1][0][0]; }
    else if (wid == 1) { gsrc = CTl + (size_t)b * 1048576 + (size_t)jblk * BLK_E; lb0 = &Al[0][0][0]; lb1 = &Al[1][0][0]; }
    else if (wid == 2) { gsrc = woh + (size_t)iblk * BLK_E; lb0 = &Bh[0][0][0]; lb1 = &Bh[1][0][0]; }
    else               { gsrc = wol + (size_t)iblk * BLK_E; lb0 = &Bl[0][0][0]; lb1 = &Bl[1][0][0]; }

    f32x4 acc[4][4] = {};

    {
        const u16* s = gsrc + lane * 8;
        u16* l = lb0 + lane * 8;
        #pragma unroll
        for (int c = 0; c < 8; c++) gload16(s + c * 512, l + c * 512);
    }
    __syncthreads();

    int buf = 0;
    for (int ks = 0; ks < 32; ks++) {
        if (ks + 1 < 32) {
            const u16* s = gsrc + (size_t)(ks + 1) * TILE_E + lane * 8;
            u16* l = (buf ? lb0 : lb1) + lane * 8;
            #pragma unroll
            for (int c = 0; c < 8; c++) gload16(s + c * 512, l + c * 512);
        }

        s16x8 fAh[4], fAl[4], fBh[4], fBl[4];
        #pragma unroll
        for (int i = 0; i < 4; i++) {
            fAh[i] = *(const s16x8*)&Ah[buf][wr * 64 + i * 16 + lrow][lk * 8];
            fAl[i] = *(const s16x8*)&Al[buf][wr * 64 + i * 16 + lrow][lk * 8];
            fBh[i] = *(const s16x8*)&Bh[buf][wc * 64 + i * 16 + lrow][lk * 8];
            fBl[i] = *(const s16x8*)&Bl[buf][wc * 64 + i * 16 + lrow][lk * 8];
        }
        __builtin_amdgcn_s_setprio(1);
        #pragma unroll
        for (int i = 0; i < 4; i++)
            #pragma unroll
            for (int j = 0; j < 4; j++) {
                acc[i][j] = MFMA(fAh[i], fBh[j], acc[i][j]);
                acc[i][j] = MFMA(fAl[i], fBh[j], acc[i][j]);
                acc[i][j] = MFMA(fAh[i], fBl[j], acc[i][j]);
            }
        __builtin_amdgcn_s_setprio(0);
        __syncthreads();
        buf ^= 1;
    }

    const int j0 = jblk * 128, i0 = iblk * 128;
    #pragma unroll
    for (int i = 0; i < 4; i++) {
        const int jj = j0 + wr * 64 + i * 16 + lk * 4;
        #pragma unroll
        for (int j = 0; j < 4; j++) {
            const int ii = i0 + wc * 64 + j * 16 + lrow;
            float* dst = out + ((size_t)b * E_ + ii) * E_ + jj;
            *(f32x4*)dst = acc[i][j];
        }
    }
}

// ---------------------------------------------------------------------------
extern "C" void kernel_launch(void* const* d_in, const int* in_sizes, int n_in,
                              void* d_out, int out_size, void* d_ws, size_t ws_size,
                              hipStream_t stream)
{
    const float* x   = (const float*)d_in[0];
    const float* Wq  = (const float*)d_in[1];
    const float* Wk  = (const float*)d_in[2];
    const float* Wv  = (const float*)d_in[3];
    const float* W_O = (const float*)d_in[4];
    float* out = (float*)d_out;

    const size_t N = (size_t)B_ * S_ * E_;   // 4,194,304
    u16* p = (u16*)d_ws;
    u16* qh  = p;            u16* ql  = p + 1 * N;
    u16* kh  = p + 2 * N;    u16* kl  = p + 3 * N;
    u16* vth = p + 4 * N;    u16* vtl = p + 5 * N;
    u16* xsh = p + 6 * N;    u16* xsl = p + 7 * N;    // tiled x; reused as CT
    u16* wth = p + 8 * N;                             // tiled W (3*E*E u16)
    u16* wtl = wth + (size_t)3 * E_ * E_;
    u16* CTh = xsh;          u16* CTl = xsl;          // alias (x dead after qkv)
    u16* woh = wth;          u16* wol = wth + (size_t)E_ * E_;  // alias (Wt dead)

    tile_rows<<<2048, 256, 0, stream>>>(x, xsh, xsl);
    tile_w<<<dim3(16, 16, 3), 256, 0, stream>>>(Wq, Wk, Wv, wth, wtl);
    qkv_gemm<<<dim3(32, 24), 256, 0, stream>>>(xsh, xsl, wth, wtl,
                                               qh, ql, kh, kl, vth, vtl);
    tile_rows<<<512, 256, 0, stream>>>(W_O, woh, wol);
    attn<<<dim3(16, 64), 256, 0, stream>>>(qh, ql, kh, kl, vth, vtl, CTh, CTl);
    out_gemm<<<dim3(8, 8, 4), 256, 0, stream>>>(CTh, CTl, woh, wol, out);
}